// Round 10
// baseline (341.668 us; speedup 1.0000x reference)
//
#include <hip/hip_runtime.h>
#include <hip/hip_bf16.h>
#include <stdint.h>

typedef __bf16 bf8 __attribute__((ext_vector_type(8)));
typedef float  f4  __attribute__((ext_vector_type(4)));

constexpr int BATCH  = 2;
constexpr int SEQ    = 2048;
constexpr int DMODEL = 1024;
constexpr int NH     = 16;
constexpr int DHEAD  = 64;
constexpr int E3     = 3072;

static __device__ __forceinline__ f4 mfma16(bf8 a, bf8 b, f4 c){
  return __builtin_amdgcn_mfma_f32_16x16x32_bf16(a, b, c, 0, 0, 0);
}
static __device__ __forceinline__ uint32_t pack2(float a, float b){
  union { __bf16 h[2]; uint32_t u; } p;
  p.h[0] = (__bf16)a; p.h[1] = (__bf16)b;
  return p.u;
}
typedef const __attribute__((address_space(1))) uint32_t g_u32;
typedef __attribute__((address_space(3))) uint32_t l_u32;
static __device__ __forceinline__ void glds16(const __bf16* g, __bf16* l){
  __builtin_amdgcn_global_load_lds((g_u32*)g, (l_u32*)l, 16, 0, 0);
}

// ---------------- fused prologue: LayerNorm + w_qkv convert ----------------
// blocks [0, 4096): LN row; blocks [4096, 7168): w_qkv fp32->bf16 (1024 elems/blk)
__global__ __launch_bounds__(256) void prep_kernel(const float* __restrict__ x,
                                                   const float* __restrict__ gam,
                                                   const float* __restrict__ bet,
                                                   __bf16* __restrict__ h,
                                                   const float* __restrict__ wq,
                                                   __bf16* __restrict__ wqb){
  int bid = blockIdx.x;
  int tid = threadIdx.x;
  if(bid >= BATCH*SEQ){
    int i = ((bid - BATCH*SEQ) * 256 + tid) * 4;
    float4 v = *(const float4*)(wq + i);
    __bf16 o[4] = {(__bf16)v.x, (__bf16)v.y, (__bf16)v.z, (__bf16)v.w};
    *(uint2*)(wqb + i) = *(const uint2*)o;
    return;
  }
  int row = bid;
  const float* xr = x + (size_t)row * DMODEL;
  float4 v = *(const float4*)(xr + tid*4);
  float s = v.x + v.y + v.z + v.w;
  float ss = v.x*v.x + v.y*v.y + v.z*v.z + v.w*v.w;
#pragma unroll
  for(int m=1;m<64;m<<=1){ s += __shfl_xor(s, m); ss += __shfl_xor(ss, m); }
  __shared__ float sm[8];
  int wid = tid >> 6;
  if((tid & 63) == 0){ sm[wid] = s; sm[4+wid] = ss; }
  __syncthreads();
  s  = sm[0]+sm[1]+sm[2]+sm[3];
  ss = sm[4]+sm[5]+sm[6]+sm[7];
  float mu  = s * (1.f/DMODEL);
  float var = ss * (1.f/DMODEL) - mu*mu;
  float r = rsqrtf(var + 1e-5f);
  float4 g = *(const float4*)(gam + tid*4);
  float4 bb = *(const float4*)(bet + tid*4);
  __bf16 o[4] = { (__bf16)((v.x-mu)*r*g.x + bb.x), (__bf16)((v.y-mu)*r*g.y + bb.y),
                  (__bf16)((v.z-mu)*r*g.z + bb.z), (__bf16)((v.w-mu)*r*g.w + bb.w) };
  *(uint2*)(h + (size_t)row*DMODEL + tid*4) = *(uint2*)o;
}

// ---------------- NT GEMM 128x128, glds staging, BK=32, DOUBLE-BUFFERED -------
template<typename CT>
__global__ __launch_bounds__(256) void gemm_nt(const __bf16* __restrict__ A,
                                               const __bf16* __restrict__ Bm,
                                               CT* __restrict__ C,
                                               int M, int Ncols, int K){
  __shared__ __align__(16) __bf16 smem[4*128*32];   // As[2] | Bs[2] (32 KB)
  __bf16* As0 = smem;
  __bf16* Bs0 = smem + 2*128*32;
  int m0 = blockIdx.y * 128, n0 = blockIdx.x * 128;
  int tid = threadIdx.x;
  int lane = tid & 63, wid = tid >> 6;
  int quad = lane >> 4, l15 = lane & 15;
  int wm = (wid >> 1) * 64, wn = (wid & 1) * 64;
  f4 acc[4][4] = {};
  int r0 = wid*32 + (lane >> 2);
  int cofs = (lane & 3) * 8;
  const __bf16* ag = A  + (size_t)(m0 + r0) * K + cofs;
  const __bf16* bg = Bm + (size_t)(n0 + r0) * K + cofs;
  const int d0 = (wid*32)*32, d1 = (wid*32+16)*32;
  const size_t rowskip = (size_t)16 * K;
  glds16(ag,           As0 + d0);
  glds16(ag + rowskip, As0 + d1);
  glds16(bg,           Bs0 + d0);
  glds16(bg + rowskip, Bs0 + d1);
  __syncthreads();
  int cur = 0;
  for(int k0 = 0; k0 < K; k0 += 32){
    int k1 = k0 + 32;
    if(k1 < K){
      int nb = cur ^ 1;
      glds16(ag + k1,           As0 + nb*128*32 + d0);
      glds16(ag + rowskip + k1, As0 + nb*128*32 + d1);
      glds16(bg + k1,           Bs0 + nb*128*32 + d0);
      glds16(bg + rowskip + k1, Bs0 + nb*128*32 + d1);
    }
    const __bf16* AsC = As0 + cur*128*32;
    const __bf16* BsC = Bs0 + cur*128*32;
    bf8 af[4], bfr[4];
#pragma unroll
    for(int i=0;i<4;i++){
      af[i]  = *(const bf8*)&AsC[(wm + i*16 + l15)*32 + quad*8];
      bfr[i] = *(const bf8*)&BsC[(wn + i*16 + l15)*32 + quad*8];
    }
#pragma unroll
    for(int mi=0;mi<4;mi++)
#pragma unroll
      for(int ni=0;ni<4;ni++)
        acc[mi][ni] = mfma16(af[mi], bfr[ni], acc[mi][ni]);
    __syncthreads();
    cur ^= 1;
  }
  if constexpr (sizeof(CT) == 2){
    __bf16* scr = smem;                      // [32][136] bf16 = 8.7 KB
    uint32_t* sp = (uint32_t*)smem;
#pragma unroll
    for(int qq=0; qq<4; qq++){
      __syncthreads();
      if((wid>>1) == (qq>>1)){
        int mi0 = (qq & 1) * 2;
#pragma unroll
        for(int mm=0; mm<2; mm++){
          int mi = mi0 + mm;
#pragma unroll
          for(int ni=0; ni<4; ni++)
#pragma unroll
            for(int r=0; r<4; r++){
              int lr = (mi - mi0)*16 + quad*4 + r;   // 0..31
              scr[lr*136 + wn + ni*16 + l15] = (__bf16)acc[mi][ni][r];
            }
        }
      }
      __syncthreads();
#pragma unroll
      for(int it=0; it<2; it++){
        int idx = it*256 + tid;              // 0..511
        int row = idx >> 4;                  // 0..31
        int ck  = idx & 15;                  // 16B chunk
        uint4 v = { sp[row*68 + ck*4 + 0], sp[row*68 + ck*4 + 1],
                    sp[row*68 + ck*4 + 2], sp[row*68 + ck*4 + 3] };
        *(uint4*)(C + (size_t)(m0 + qq*32 + row)*Ncols + n0 + ck*8) = v;
      }
    }
  } else {
    float* scr = (float*)smem;               // [32][136] f32 = 17.4 KB (< 32 KB)
#pragma unroll
    for(int qq=0; qq<4; qq++){
      __syncthreads();
      if((wid>>1) == (qq>>1)){
        int mi0 = (qq & 1) * 2;
#pragma unroll
        for(int mm=0; mm<2; mm++){
          int mi = mi0 + mm;
#pragma unroll
          for(int ni=0; ni<4; ni++)
#pragma unroll
            for(int r=0; r<4; r++){
              int lr = (mi - mi0)*16 + quad*4 + r;   // 0..31
              scr[lr*136 + wn + ni*16 + l15] = acc[mi][ni][r];
            }
        }
      }
      __syncthreads();
#pragma unroll
      for(int it=0; it<4; it++){
        int idx = it*256 + tid;              // 0..1023
        int row = idx >> 5;                  // 0..31
        int ck  = idx & 31;                  // 16B chunk (4 f32)
        float4 v = { scr[row*136 + ck*4 + 0], scr[row*136 + ck*4 + 1],
                     scr[row*136 + ck*4 + 2], scr[row*136 + ck*4 + 3] };
        *(float4*)(C + (size_t)(m0 + qq*32 + row)*Ncols + n0 + ck*4) = v;
      }
    }
  }
}

// ---------------- grouped depthwise causal conv, LDS-tiled input ----------------
// (R9 scratch-fix version: block-uniform weight select, named registers)
__global__ __launch_bounds__(256) void conv_kernel(const __bf16* __restrict__ qkv,
    __bf16* __restrict__ qo, __bf16* __restrict__ ko, __bf16* __restrict__ vt,
    const float* qw3,const float* qb3,const float* qw5,const float* qb5,const float* qw7,const float* qb7,
    const float* kw3,const float* kb3,const float* kw5,const float* kb5,const float* kw7,const float* kb7,
    const float* vw3,const float* vb3,const float* vw5,const float* vb5,const float* vw7,const float* vb7){
  __shared__ __align__(16) __bf16 tile[72*256];   // rows: n0-8 .. n0+63
  int nc = blockIdx.x;      // 32 chunks of 64 along N
  int ec = blockIdx.y;      // 12 chunks of 256 channels
  int b  = blockIdx.z;
  int tid = threadIdx.x;
  int n0 = nc * 64;
  {
    int rrow = tid >> 5;          // 0..7
    int ccol = (tid & 31) * 8;    // 0..248
    const __bf16* src = qkv + (size_t)b*SEQ*E3 + ec*256 + ccol;
#pragma unroll
    for(int p=0;p<9;p++){
      int row = p*8 + rrow;
      int n = n0 - 8 + row;
      uint4 v = {0u,0u,0u,0u};
      if(n >= 0) v = *(const uint4*)(src + (size_t)n*E3);
      *(uint4*)&tile[row*256 + ccol] = v;
    }
  }
  __syncthreads();
  int p = ec >> 2;          // 0=Q, 1=K, 2=V   (block-uniform)
  int g = ec & 3;           // 0=id, 1=k3, 2=k5, 3=k7   (block-uniform)
  float w0=0.f,w1=0.f,w2=0.f,w3=0.f,w4=0.f,w5=0.f,w6=0.f,bias=0.f;
  if(g == 1){
    const float* wp = (p==0)? qw3 : (p==1)? kw3 : vw3;
    const float* bp = (p==0)? qb3 : (p==1)? kb3 : vb3;
    w0 = wp[tid*3+0]; w1 = wp[tid*3+1]; w2 = wp[tid*3+2]; bias = bp[tid];
  } else if(g == 2){
    const float* wp = (p==0)? qw5 : (p==1)? kw5 : vw5;
    const float* bp = (p==0)? qb5 : (p==1)? kb5 : vb5;
    w0 = wp[tid*5+0]; w1 = wp[tid*5+1]; w2 = wp[tid*5+2];
    w3 = wp[tid*5+3]; w4 = wp[tid*5+4]; bias = bp[tid];
  } else if(g == 3){
    const float* wp = (p==0)? qw7 : (p==1)? kw7 : vw7;
    const float* bp = (p==0)? qb7 : (p==1)? kb7 : vb7;
    w0 = wp[tid*7+0]; w1 = wp[tid*7+1]; w2 = wp[tid*7+2]; w3 = wp[tid*7+3];
    w4 = wp[tid*7+4]; w5 = wp[tid*7+5]; w6 = wp[tid*7+6]; bias = bp[tid];
  }
  float x0 = (float)tile[2*256 + tid];
  float x1 = (float)tile[3*256 + tid];
  float x2 = (float)tile[4*256 + tid];
  float x3 = (float)tile[5*256 + tid];
  float x4 = (float)tile[6*256 + tid];
  float x5 = (float)tile[7*256 + tid];
#define CONV_STEP(cur, o)                                                      \
  { if(g == 0)      o = (cur);                                                 \
    else if(g == 1) o = w0*x4 + w1*x5 + w2*(cur) + bias;                       \
    else if(g == 2) o = w0*x2 + w1*x3 + w2*x4 + w3*x5 + w4*(cur) + bias;       \
    else            o = w0*x0 + w1*x1 + w2*x2 + w3*x3 + w4*x4 + w5*x5          \
                        + w6*(cur) + bias;                                     \
    x0=x1; x1=x2; x2=x3; x3=x4; x4=x5; x5=(cur); }
  if(p == 2){
    uint32_t vout[32];
#pragma unroll
    for(int blk=0; blk<8; blk++){
#pragma unroll
      for(int up=0; up<4; up++){
        float ca = (float)tile[(8 + blk*8 + up*2    )*256 + tid];
        float oa; CONV_STEP(ca, oa);
        float cb = (float)tile[(8 + blk*8 + up*2 + 1)*256 + tid];
        float ob; CONV_STEP(cb, ob);
        vout[blk*4 + up] = pack2(oa, ob);
      }
    }
    __syncthreads();                         // all tile reads done
    uint32_t* ot = (uint32_t*)tile;          // reuse as [256 ch][33 u32] (padded)
#pragma unroll
    for(int j=0;j<32;j++) ot[tid*33 + j] = vout[j];
    __syncthreads();
#pragma unroll
    for(int it=0; it<8; it++){
      int idx = it*256 + tid;                // 0..2047
      int ch  = idx >> 3;                    // local channel 0..255
      int ncq = idx & 7;                     // 16B chunk along n
      uint4 val = { ot[ch*33 + ncq*4 + 0], ot[ch*33 + ncq*4 + 1],
                    ot[ch*33 + ncq*4 + 2], ot[ch*33 + ncq*4 + 3] };
      int hh2 = g*4 + (ch >> 6);
      int dh2 = ch & 63;
      *(uint4*)(vt + ((size_t)((b*NH + hh2)*DHEAD + dh2))*SEQ + n0 + ncq*8) = val;
    }
  } else {
    int hh = g*4 + (tid >> 6);
    int dh = tid & 63;
    __bf16* outp = (p==0) ? qo : ko;
    __bf16* op = outp + ((size_t)(b*NH + hh)*SEQ)*DHEAD + dh;
#pragma unroll 8
    for(int dn=0; dn<64; dn++){
      float cur = (float)tile[(8+dn)*256 + tid];
      float o; CONV_STEP(cur, o);
      op[(size_t)(n0+dn)*DHEAD] = (__bf16)o;
    }
  }
#undef CONV_STEP
}

// ---------------- flash attention + fused w_out convert ----------------
// LDS-THROUGHPUT build: QBLK=128, each wave owns 32 q-rows as TWO 16-col MFMA
// groups -> every K-frag and V-frag LDS read is reused for 2 MFMAs (DS ops per
// FLOP -45%; R9 analysis: DS pipe was ~2/3 busy = the bound). KVBLK=64 dbuf,
// glds staging, 50.5 KB LDS -> 3 blocks/CU. Grid: 512 attn blocks with
// ANTITHETIC pairing (bid<256: qi=15-(bid>>5); else qi=(bid>>5)-8) so the two
// blocks a CU hosts sum to a constant 34 iters AND share the same head (L2).
// XCD pin: bid&7 == head&7. Blocks [512,1536): w_out fp32->bf16.
__global__ __launch_bounds__(256, 3) void attn_kernel(const __bf16* __restrict__ Qin,
                                                      const __bf16* __restrict__ Kin,
                                                      const __bf16* __restrict__ Vtin,
                                                      const float* __restrict__ slopes,
                                                      __bf16* __restrict__ Oout,
                                                      const float* __restrict__ wsrc,
                                                      __bf16* __restrict__ wdst){
  __shared__ __align__(16) __bf16 Ks[2][64*64];     // 16 KB
  __shared__ __align__(16) __bf16 Vts[2][64*64];    // 16 KB
  __shared__ __align__(16) __bf16 Ps[4][2][16*72];  // 18 KB (per wave, per qg)
  __shared__ float Al[4][2][16];
  int bid = blockIdx.x;
  int tid = threadIdx.x;
  if(bid >= 512){
    int i = ((bid - 512) * 256 + tid) * 4;
    float4 v = *(const float4*)(wsrc + i);
    __bf16 o[4] = {(__bf16)v.x, (__bf16)v.y, (__bf16)v.z, (__bf16)v.w};
    *(uint2*)(wdst + i) = *(const uint2*)o;
    return;
  }
  int qi = (bid < 256) ? (15 - (bid >> 5)) : ((bid >> 5) - 8);
  int by = (bid & 7) + ((bid >> 3) & 3) * 8;      // 0..31, by%8 == bid%8 (XCD pin)
  int b  = by >> 4, hh = by & 15;
  int lane = tid & 63, w = tid >> 6;
  int quad = lane >> 4, l15 = lane & 15;
  const __bf16* qb  = Qin  + (size_t)by * SEQ * DHEAD;
  const __bf16* kb  = Kin  + (size_t)by * SEQ * DHEAD;
  const __bf16* vtb = Vtin + (size_t)by * DHEAD * SEQ;
  const float L2E = 1.4426950408889634f;
  float slope = slopes[hh];
  const float c1 = 0.125f * L2E;
  float c2 = slope * L2E;
  float cjb[16];
#pragma unroll
  for(int jt=0;jt<4;jt++)
#pragma unroll
    for(int r=0;r<4;r++)
      cjb[jt*4+r] = c2 * (float)(jt*16 + quad*4 + r);

  int sxq0 = ((quad     ^ (l15 & 7)) << 3);   // d 0..31
  int sxq1 = (((quad+4) ^ (l15 & 7)) << 3);   // d 32..63

  int r8 = lane >> 3;              // 0..7 (row within staging group)
  int c8 = lane & 7;
  int sw = (c8 ^ r8) * 8;          // inverse-swizzled source chunk
  const __bf16* ksrc = kb  + (size_t)r8*DHEAD + sw;
  const __bf16* vsrc = vtb + (size_t)r8*SEQ  + sw;
  int g0 = w*2, g1 = w*2 + 1;
  const size_t kg0o = (size_t)g0*8*DHEAD, kg1o = (size_t)g1*8*DHEAD;
  const size_t vg0o = (size_t)g0*8*SEQ,   vg1o = (size_t)g1*8*SEQ;

  int q0 = qi * 128;
  int nst = 2*qi + 2;                        // k-tiles of 64
  int ig0 = q0 + w*32 + l15;                 // qg=0 q-row
  int ig1 = ig0 + 16;                        // qg=1 q-row
  bf8 aq00 = *(const bf8*)(qb + (size_t)ig0*DHEAD + quad*8);
  bf8 aq01 = *(const bf8*)(qb + (size_t)ig0*DHEAD + 32 + quad*8);
  bf8 aq10 = *(const bf8*)(qb + (size_t)ig1*DHEAD + quad*8);
  bf8 aq11 = *(const bf8*)(qb + (size_t)ig1*DHEAD + 32 + quad*8);
  f4 oacc0[4] = {}, oacc1[4] = {};
  float l_0 = 0.f, l_1 = 0.f;
  glds16(ksrc + kg0o, &Ks[0][g0*512]);
  glds16(ksrc + kg1o, &Ks[0][g1*512]);
  glds16(vsrc + vg0o, &Vts[0][g0*512]);
  glds16(vsrc + vg1o, &Vts[0][g1*512]);
  __syncthreads();
  int cur = 0;
  for(int t=0; t<nst; t++){
    int j0 = t*64;
    bool pf = (t+1) < nst;
    if(pf){
      int nb = cur ^ 1;
      size_t off = (size_t)(t+1)*64;
      glds16(ksrc + off*DHEAD + kg0o, &Ks[nb][g0*512]);
      glds16(ksrc + off*DHEAD + kg1o, &Ks[nb][g1*512]);
      glds16(vsrc + vg0o + off,       &Vts[nb][g0*512]);
      glds16(vsrc + vg1o + off,       &Vts[nb][g1*512]);
    }
    const __bf16* KsC  = Ks[cur];
    const __bf16* VtsC = Vts[cur];
    f4 s0[4] = {}, s1[4] = {};
    __builtin_amdgcn_s_setprio(1);
#pragma unroll
    for(int jt=0;jt<4;jt++){
      bf8 ak0 = *(const bf8*)&KsC[(jt*16+l15)*64 + sxq0];
      bf8 ak1 = *(const bf8*)&KsC[(jt*16+l15)*64 + sxq1];
      s0[jt] = mfma16(ak0, aq00, s0[jt]);
      s0[jt] = mfma16(ak1, aq01, s0[jt]);
      s1[jt] = mfma16(ak0, aq10, s1[jt]);
      s1[jt] = mfma16(ak1, aq11, s1[jt]);
    }
    __builtin_amdgcn_s_setprio(0);
    // hoist V-frag reads (reused for both q-groups)
    bf8 bv[2][4];
#pragma unroll
    for(int jk=0;jk<2;jk++)
#pragma unroll
      for(int nd=0;nd<4;nd++)
        bv[jk][nd] = *(const bf8*)&VtsC[(nd*16+l15)*64 + (((jk*4+quad) ^ (l15&7)) << 3)];
    bool masked = (t >= nst-2);
#pragma unroll
    for(int qg=0; qg<2; qg++){
      const f4* sq = qg ? s1 : s0;
      int iq = qg ? ig1 : ig0;
      float sv[4][4];
      if(!masked){
        float cdi = c2 * (float)(iq - j0) + 8.0f;
#pragma unroll
        for(int jt=0;jt<4;jt++)
#pragma unroll
          for(int r=0;r<4;r++)
            sv[jt][r] = fmaf(sq[jt][r], c1, cjb[jt*4+r] - cdi);
      } else {
#pragma unroll
        for(int jt=0;jt<4;jt++)
#pragma unroll
          for(int r=0;r<4;r++){
            int j = j0 + jt*16 + quad*4 + r;
            int d = iq - j;
            float val = fmaf(sq[jt][r], c1, -fmaf(c2, (float)d, 8.0f));
            sv[jt][r] = (d < 0) ? -1e30f : val;
          }
      }
      float lsum = 0.f;
#pragma unroll
      for(int jt=0;jt<4;jt++){
        float p0 = __builtin_amdgcn_exp2f(sv[jt][0]);
        float p1 = __builtin_amdgcn_exp2f(sv[jt][1]);
        float p2 = __builtin_amdgcn_exp2f(sv[jt][2]);
        float p3 = __builtin_amdgcn_exp2f(sv[jt][3]);
        lsum += (p0+p1)+(p2+p3);
        uint2 pk = { pack2(p0,p1), pack2(p2,p3) };
        *(uint2*)&Ps[w][qg][l15*72 + jt*16 + quad*4] = pk;
      }
      lsum += __shfl_xor(lsum, 16);
      lsum += __shfl_xor(lsum, 32);
      if(qg) l_1 += lsum; else l_0 += lsum;
    }
    __builtin_amdgcn_s_setprio(1);
#pragma unroll
    for(int jk=0;jk<2;jk++){
      bf8 ap0 = *(const bf8*)&Ps[w][0][l15*72 + jk*32 + quad*8];
      bf8 ap1 = *(const bf8*)&Ps[w][1][l15*72 + jk*32 + quad*8];
#pragma unroll
      for(int nd=0;nd<4;nd++){
        oacc0[nd] = mfma16(ap0, bv[jk][nd], oacc0[nd]);
        oacc1[nd] = mfma16(ap1, bv[jk][nd], oacc1[nd]);
      }
    }
    __builtin_amdgcn_s_setprio(0);
    __syncthreads();
    cur ^= 1;
  }
  if(quad == 0){ Al[w][0][l15] = 1.0f / l_0; Al[w][1][l15] = 1.0f / l_1; }
  f4 linv0 = *(const f4*)&Al[w][0][quad*4];
  f4 linv1 = *(const f4*)&Al[w][1][quad*4];
#pragma unroll
  for(int nd=0;nd<4;nd++)
#pragma unroll
    for(int r=0;r<4;r++){
      int io0 = q0 + w*32 + quad*4 + r;
      Oout[((size_t)(b*SEQ + io0))*DMODEL + hh*64 + nd*16 + l15] =
          (__bf16)(oacc0[nd][r] * linv0[r]);
      Oout[((size_t)(b*SEQ + io0 + 16))*DMODEL + hh*64 + nd*16 + l15] =
          (__bf16)(oacc1[nd][r] * linv1[r]);
    }
}

extern "C" void kernel_launch(void* const* d_in, const int* in_sizes, int n_in,
                              void* d_out, int out_size, void* d_ws, size_t ws_size,
                              hipStream_t stream){
  const float* x      = (const float*)d_in[0];
  const float* gam    = (const float*)d_in[1];
  const float* bet    = (const float*)d_in[2];
  const float* w_qkv  = (const float*)d_in[3];
  const float* slopes = (const float*)d_in[22];
  const float* w_out  = (const float*)d_in[23];
  float* out = (float*)d_out;

  // 48 MB workspace, aliased by liveness (proven at 48 MB):
  // [0,8)   h -> qpost
  // [8,32)  qkv -> att [8,16), wout_bf [24,26) (after conv)
  // [32,38) wqkv_bf -> kpost [32,40) (after gemm1)
  // [40,48) vtp (written by conv directly, transposed)
  char* ws = (char*)d_ws;
  __bf16* h       = (__bf16*)(ws);
  __bf16* qpost   = (__bf16*)(ws);
  __bf16* qkv     = (__bf16*)(ws + ((size_t)8  << 20));
  __bf16* att     = (__bf16*)(ws + ((size_t)8  << 20));
  __bf16* wout_bf = (__bf16*)(ws + ((size_t)24 << 20));
  __bf16* wqkv_bf = (__bf16*)(ws + ((size_t)32 << 20));
  __bf16* kpost   = (__bf16*)(ws + ((size_t)32 << 20));
  __bf16* vtp     = (__bf16*)(ws + ((size_t)40 << 20));

  constexpr int NQKV = 3 * DMODEL * DMODEL;

  prep_kernel<<<BATCH*SEQ + NQKV/4/256, 256, 0, stream>>>(x, gam, bet, h, w_qkv, wqkv_bf);
  gemm_nt<__bf16><<<dim3(E3/128, (BATCH*SEQ)/128), 256, 0, stream>>>(
      h, wqkv_bf, qkv, BATCH*SEQ, E3, DMODEL);
  conv_kernel<<<dim3(32, 12, BATCH), 256, 0, stream>>>(qkv, qpost, kpost, vtp,
    (const float*)d_in[4],(const float*)d_in[5],(const float*)d_in[6],(const float*)d_in[7],
    (const float*)d_in[8],(const float*)d_in[9],
    (const float*)d_in[10],(const float*)d_in[11],(const float*)d_in[12],(const float*)d_in[13],
    (const float*)d_in[14],(const float*)d_in[15],
    (const float*)d_in[16],(const float*)d_in[17],(const float*)d_in[18],(const float*)d_in[19],
    (const float*)d_in[20],(const float*)d_in[21]);
  attn_kernel<<<dim3(1536), 256, 0, stream>>>(qpost, kpost, vtp, slopes, att,
                                              w_out, wout_bf);
  gemm_nt<float><<<dim3(DMODEL/128, (BATCH*SEQ)/128), 256, 0, stream>>>(
      att, wout_bf, out, BATCH*SEQ, DMODEL, DMODEL);
}

// Round 11
// 240.394 us; speedup vs baseline: 1.4213x; 1.4213x over previous
//
#include <hip/hip_runtime.h>
#include <hip/hip_bf16.h>
#include <stdint.h>

typedef __bf16 bf8 __attribute__((ext_vector_type(8)));
typedef float  f4  __attribute__((ext_vector_type(4)));

constexpr int BATCH  = 2;
constexpr int SEQ    = 2048;
constexpr int DMODEL = 1024;
constexpr int NH     = 16;
constexpr int DHEAD  = 64;
constexpr int E3     = 3072;

static __device__ __forceinline__ f4 mfma16(bf8 a, bf8 b, f4 c){
  return __builtin_amdgcn_mfma_f32_16x16x32_bf16(a, b, c, 0, 0, 0);
}
static __device__ __forceinline__ uint32_t pack2(float a, float b){
  union { __bf16 h[2]; uint32_t u; } p;
  p.h[0] = (__bf16)a; p.h[1] = (__bf16)b;
  return p.u;
}
typedef const __attribute__((address_space(1))) uint32_t g_u32;
typedef __attribute__((address_space(3))) uint32_t l_u32;
static __device__ __forceinline__ void glds16(const __bf16* g, __bf16* l){
  __builtin_amdgcn_global_load_lds((g_u32*)g, (l_u32*)l, 16, 0, 0);
}

// ---------------- fused prologue: LayerNorm + w_qkv convert ----------------
// blocks [0, 4096): LN row; blocks [4096, 7168): w_qkv fp32->bf16 (1024 elems/blk)
__global__ __launch_bounds__(256) void prep_kernel(const float* __restrict__ x,
                                                   const float* __restrict__ gam,
                                                   const float* __restrict__ bet,
                                                   __bf16* __restrict__ h,
                                                   const float* __restrict__ wq,
                                                   __bf16* __restrict__ wqb){
  int bid = blockIdx.x;
  int tid = threadIdx.x;
  if(bid >= BATCH*SEQ){
    int i = ((bid - BATCH*SEQ) * 256 + tid) * 4;
    float4 v = *(const float4*)(wq + i);
    __bf16 o[4] = {(__bf16)v.x, (__bf16)v.y, (__bf16)v.z, (__bf16)v.w};
    *(uint2*)(wqb + i) = *(const uint2*)o;
    return;
  }
  int row = bid;
  const float* xr = x + (size_t)row * DMODEL;
  float4 v = *(const float4*)(xr + tid*4);
  float s = v.x + v.y + v.z + v.w;
  float ss = v.x*v.x + v.y*v.y + v.z*v.z + v.w*v.w;
#pragma unroll
  for(int m=1;m<64;m<<=1){ s += __shfl_xor(s, m); ss += __shfl_xor(ss, m); }
  __shared__ float sm[8];
  int wid = tid >> 6;
  if((tid & 63) == 0){ sm[wid] = s; sm[4+wid] = ss; }
  __syncthreads();
  s  = sm[0]+sm[1]+sm[2]+sm[3];
  ss = sm[4]+sm[5]+sm[6]+sm[7];
  float mu  = s * (1.f/DMODEL);
  float var = ss * (1.f/DMODEL) - mu*mu;
  float r = rsqrtf(var + 1e-5f);
  float4 g = *(const float4*)(gam + tid*4);
  float4 bb = *(const float4*)(bet + tid*4);
  __bf16 o[4] = { (__bf16)((v.x-mu)*r*g.x + bb.x), (__bf16)((v.y-mu)*r*g.y + bb.y),
                  (__bf16)((v.z-mu)*r*g.z + bb.z), (__bf16)((v.w-mu)*r*g.w + bb.w) };
  *(uint2*)(h + (size_t)row*DMODEL + tid*4) = *(uint2*)o;
}

// ---------------- NT GEMM 128x128, glds staging, BK=32, DOUBLE-BUFFERED -------
template<typename CT>
__global__ __launch_bounds__(256) void gemm_nt(const __bf16* __restrict__ A,
                                               const __bf16* __restrict__ Bm,
                                               CT* __restrict__ C,
                                               int M, int Ncols, int K){
  __shared__ __align__(16) __bf16 smem[4*128*32];   // As[2] | Bs[2] (32 KB)
  __bf16* As0 = smem;
  __bf16* Bs0 = smem + 2*128*32;
  int m0 = blockIdx.y * 128, n0 = blockIdx.x * 128;
  int tid = threadIdx.x;
  int lane = tid & 63, wid = tid >> 6;
  int quad = lane >> 4, l15 = lane & 15;
  int wm = (wid >> 1) * 64, wn = (wid & 1) * 64;
  f4 acc[4][4] = {};
  int r0 = wid*32 + (lane >> 2);
  int cofs = (lane & 3) * 8;
  const __bf16* ag = A  + (size_t)(m0 + r0) * K + cofs;
  const __bf16* bg = Bm + (size_t)(n0 + r0) * K + cofs;
  const int d0 = (wid*32)*32, d1 = (wid*32+16)*32;
  const size_t rowskip = (size_t)16 * K;
  glds16(ag,           As0 + d0);
  glds16(ag + rowskip, As0 + d1);
  glds16(bg,           Bs0 + d0);
  glds16(bg + rowskip, Bs0 + d1);
  __syncthreads();
  int cur = 0;
  for(int k0 = 0; k0 < K; k0 += 32){
    int k1 = k0 + 32;
    if(k1 < K){
      int nb = cur ^ 1;
      glds16(ag + k1,           As0 + nb*128*32 + d0);
      glds16(ag + rowskip + k1, As0 + nb*128*32 + d1);
      glds16(bg + k1,           Bs0 + nb*128*32 + d0);
      glds16(bg + rowskip + k1, Bs0 + nb*128*32 + d1);
    }
    const __bf16* AsC = As0 + cur*128*32;
    const __bf16* BsC = Bs0 + cur*128*32;
    bf8 af[4], bfr[4];
#pragma unroll
    for(int i=0;i<4;i++){
      af[i]  = *(const bf8*)&AsC[(wm + i*16 + l15)*32 + quad*8];
      bfr[i] = *(const bf8*)&BsC[(wn + i*16 + l15)*32 + quad*8];
    }
#pragma unroll
    for(int mi=0;mi<4;mi++)
#pragma unroll
      for(int ni=0;ni<4;ni++)
        acc[mi][ni] = mfma16(af[mi], bfr[ni], acc[mi][ni]);
    __syncthreads();
    cur ^= 1;
  }
  if constexpr (sizeof(CT) == 2){
    __bf16* scr = smem;                      // [32][136] bf16 = 8.7 KB
    uint32_t* sp = (uint32_t*)smem;
#pragma unroll
    for(int qq=0; qq<4; qq++){
      __syncthreads();
      if((wid>>1) == (qq>>1)){
        int mi0 = (qq & 1) * 2;
#pragma unroll
        for(int mm=0; mm<2; mm++){
          int mi = mi0 + mm;
#pragma unroll
          for(int ni=0; ni<4; ni++)
#pragma unroll
            for(int r=0; r<4; r++){
              int lr = (mi - mi0)*16 + quad*4 + r;   // 0..31
              scr[lr*136 + wn + ni*16 + l15] = (__bf16)acc[mi][ni][r];
            }
        }
      }
      __syncthreads();
#pragma unroll
      for(int it=0; it<2; it++){
        int idx = it*256 + tid;              // 0..511
        int row = idx >> 4;                  // 0..31
        int ck  = idx & 15;                  // 16B chunk
        uint4 v = { sp[row*68 + ck*4 + 0], sp[row*68 + ck*4 + 1],
                    sp[row*68 + ck*4 + 2], sp[row*68 + ck*4 + 3] };
        *(uint4*)(C + (size_t)(m0 + qq*32 + row)*Ncols + n0 + ck*8) = v;
      }
    }
  } else {
    float* scr = (float*)smem;               // [32][136] f32 = 17.4 KB (< 32 KB)
#pragma unroll
    for(int qq=0; qq<4; qq++){
      __syncthreads();
      if((wid>>1) == (qq>>1)){
        int mi0 = (qq & 1) * 2;
#pragma unroll
        for(int mm=0; mm<2; mm++){
          int mi = mi0 + mm;
#pragma unroll
          for(int ni=0; ni<4; ni++)
#pragma unroll
            for(int r=0; r<4; r++){
              int lr = (mi - mi0)*16 + quad*4 + r;   // 0..31
              scr[lr*136 + wn + ni*16 + l15] = acc[mi][ni][r];
            }
        }
      }
      __syncthreads();
#pragma unroll
      for(int it=0; it<4; it++){
        int idx = it*256 + tid;              // 0..1023
        int row = idx >> 5;                  // 0..31
        int ck  = idx & 31;                  // 16B chunk (4 f32)
        float4 v = { scr[row*136 + ck*4 + 0], scr[row*136 + ck*4 + 1],
                     scr[row*136 + ck*4 + 2], scr[row*136 + ck*4 + 3] };
        *(float4*)(C + (size_t)(m0 + qq*32 + row)*Ncols + n0 + ck*4) = v;
      }
    }
  }
}

// ---------------- grouped depthwise causal conv, LDS-tiled input ----------------
// (R9 scratch-fix version: block-uniform weight select, named registers)
__global__ __launch_bounds__(256) void conv_kernel(const __bf16* __restrict__ qkv,
    __bf16* __restrict__ qo, __bf16* __restrict__ ko, __bf16* __restrict__ vt,
    const float* qw3,const float* qb3,const float* qw5,const float* qb5,const float* qw7,const float* qb7,
    const float* kw3,const float* kb3,const float* kw5,const float* kb5,const float* kw7,const float* kb7,
    const float* vw3,const float* vb3,const float* vw5,const float* vb5,const float* vw7,const float* vb7){
  __shared__ __align__(16) __bf16 tile[72*256];   // rows: n0-8 .. n0+63
  int nc = blockIdx.x;      // 32 chunks of 64 along N
  int ec = blockIdx.y;      // 12 chunks of 256 channels
  int b  = blockIdx.z;
  int tid = threadIdx.x;
  int n0 = nc * 64;
  {
    int rrow = tid >> 5;          // 0..7
    int ccol = (tid & 31) * 8;    // 0..248
    const __bf16* src = qkv + (size_t)b*SEQ*E3 + ec*256 + ccol;
#pragma unroll
    for(int p=0;p<9;p++){
      int row = p*8 + rrow;
      int n = n0 - 8 + row;
      uint4 v = {0u,0u,0u,0u};
      if(n >= 0) v = *(const uint4*)(src + (size_t)n*E3);
      *(uint4*)&tile[row*256 + ccol] = v;
    }
  }
  __syncthreads();
  int p = ec >> 2;          // 0=Q, 1=K, 2=V   (block-uniform)
  int g = ec & 3;           // 0=id, 1=k3, 2=k5, 3=k7   (block-uniform)
  float w0=0.f,w1=0.f,w2=0.f,w3=0.f,w4=0.f,w5=0.f,w6=0.f,bias=0.f;
  if(g == 1){
    const float* wp = (p==0)? qw3 : (p==1)? kw3 : vw3;
    const float* bp = (p==0)? qb3 : (p==1)? kb3 : vb3;
    w0 = wp[tid*3+0]; w1 = wp[tid*3+1]; w2 = wp[tid*3+2]; bias = bp[tid];
  } else if(g == 2){
    const float* wp = (p==0)? qw5 : (p==1)? kw5 : vw5;
    const float* bp = (p==0)? qb5 : (p==1)? kb5 : vb5;
    w0 = wp[tid*5+0]; w1 = wp[tid*5+1]; w2 = wp[tid*5+2];
    w3 = wp[tid*5+3]; w4 = wp[tid*5+4]; bias = bp[tid];
  } else if(g == 3){
    const float* wp = (p==0)? qw7 : (p==1)? kw7 : vw7;
    const float* bp = (p==0)? qb7 : (p==1)? kb7 : vb7;
    w0 = wp[tid*7+0]; w1 = wp[tid*7+1]; w2 = wp[tid*7+2]; w3 = wp[tid*7+3];
    w4 = wp[tid*7+4]; w5 = wp[tid*7+5]; w6 = wp[tid*7+6]; bias = bp[tid];
  }
  float x0 = (float)tile[2*256 + tid];
  float x1 = (float)tile[3*256 + tid];
  float x2 = (float)tile[4*256 + tid];
  float x3 = (float)tile[5*256 + tid];
  float x4 = (float)tile[6*256 + tid];
  float x5 = (float)tile[7*256 + tid];
#define CONV_STEP(cur, o)                                                      \
  { if(g == 0)      o = (cur);                                                 \
    else if(g == 1) o = w0*x4 + w1*x5 + w2*(cur) + bias;                       \
    else if(g == 2) o = w0*x2 + w1*x3 + w2*x4 + w3*x5 + w4*(cur) + bias;       \
    else            o = w0*x0 + w1*x1 + w2*x2 + w3*x3 + w4*x4 + w5*x5          \
                        + w6*(cur) + bias;                                     \
    x0=x1; x1=x2; x2=x3; x3=x4; x4=x5; x5=(cur); }
  if(p == 2){
    uint32_t vout[32];
#pragma unroll
    for(int blk=0; blk<8; blk++){
#pragma unroll
      for(int up=0; up<4; up++){
        float ca = (float)tile[(8 + blk*8 + up*2    )*256 + tid];
        float oa; CONV_STEP(ca, oa);
        float cb = (float)tile[(8 + blk*8 + up*2 + 1)*256 + tid];
        float ob; CONV_STEP(cb, ob);
        vout[blk*4 + up] = pack2(oa, ob);
      }
    }
    __syncthreads();                         // all tile reads done
    uint32_t* ot = (uint32_t*)tile;          // reuse as [256 ch][33 u32] (padded)
#pragma unroll
    for(int j=0;j<32;j++) ot[tid*33 + j] = vout[j];
    __syncthreads();
#pragma unroll
    for(int it=0; it<8; it++){
      int idx = it*256 + tid;                // 0..2047
      int ch  = idx >> 3;                    // local channel 0..255
      int ncq = idx & 7;                     // 16B chunk along n
      uint4 val = { ot[ch*33 + ncq*4 + 0], ot[ch*33 + ncq*4 + 1],
                    ot[ch*33 + ncq*4 + 2], ot[ch*33 + ncq*4 + 3] };
      int hh2 = g*4 + (ch >> 6);
      int dh2 = ch & 63;
      *(uint4*)(vt + ((size_t)((b*NH + hh2)*DHEAD + dh2))*SEQ + n0 + ncq*8) = val;
    }
  } else {
    int hh = g*4 + (tid >> 6);
    int dh = tid & 63;
    __bf16* outp = (p==0) ? qo : ko;
    __bf16* op = outp + ((size_t)(b*NH + hh)*SEQ)*DHEAD + dh;
#pragma unroll 8
    for(int dn=0; dn<64; dn++){
      float cur = (float)tile[(8+dn)*256 + tid];
      float o; CONV_STEP(cur, o);
      op[(size_t)(n0+dn)*DHEAD] = (__bf16)o;
    }
  }
#undef CONV_STEP
}

// ---------------- flash attention + fused w_out convert ----------------
// QBLK=128 K/V-reuse build, SPILL-FIXED: R10's launch_bounds(256,3) capped
// VGPRs at 84 (< the ~180 live state) -> accumulator spill to scratch
// (WRITE_SIZE 10->56 MB, 159 us). Fix: (256,2) -> 256-VGPR budget, no spill;
// 2 blocks/CU, grid 512 = exactly resident, antithetic pairing (bid c <-> c+256:
// same head, qi pair sums to 15 -> constant 34 iters/CU). DS-ops/FLOP -36% vs
// R9 via K/V-frag reuse across two q-groups. XCD pin: bid&7 == head&7.
// Blocks [512,1536): w_out fp32->bf16.
__global__ __launch_bounds__(256, 2) void attn_kernel(const __bf16* __restrict__ Qin,
                                                      const __bf16* __restrict__ Kin,
                                                      const __bf16* __restrict__ Vtin,
                                                      const float* __restrict__ slopes,
                                                      __bf16* __restrict__ Oout,
                                                      const float* __restrict__ wsrc,
                                                      __bf16* __restrict__ wdst){
  __shared__ __align__(16) __bf16 Ks[2][64*64];     // 16 KB
  __shared__ __align__(16) __bf16 Vts[2][64*64];    // 16 KB
  __shared__ __align__(16) __bf16 Ps[4][2][16*72];  // 18 KB (per wave, per qg)
  __shared__ float Al[4][2][16];
  int bid = blockIdx.x;
  int tid = threadIdx.x;
  if(bid >= 512){
    int i = ((bid - 512) * 256 + tid) * 4;
    float4 v = *(const float4*)(wsrc + i);
    __bf16 o[4] = {(__bf16)v.x, (__bf16)v.y, (__bf16)v.z, (__bf16)v.w};
    *(uint2*)(wdst + i) = *(const uint2*)o;
    return;
  }
  int qi = (bid < 256) ? (15 - (bid >> 5)) : ((bid >> 5) - 8);
  int by = (bid & 7) + ((bid >> 3) & 3) * 8;      // 0..31, by%8 == bid%8 (XCD pin)
  int b  = by >> 4, hh = by & 15;
  int lane = tid & 63, w = tid >> 6;
  int quad = lane >> 4, l15 = lane & 15;
  const __bf16* qb  = Qin  + (size_t)by * SEQ * DHEAD;
  const __bf16* kb  = Kin  + (size_t)by * SEQ * DHEAD;
  const __bf16* vtb = Vtin + (size_t)by * DHEAD * SEQ;
  const float L2E = 1.4426950408889634f;
  float slope = slopes[hh];
  const float c1 = 0.125f * L2E;
  float c2 = slope * L2E;
  float cjb[16];
#pragma unroll
  for(int jt=0;jt<4;jt++)
#pragma unroll
    for(int r=0;r<4;r++)
      cjb[jt*4+r] = c2 * (float)(jt*16 + quad*4 + r);

  int sxq0 = ((quad     ^ (l15 & 7)) << 3);   // d 0..31
  int sxq1 = (((quad+4) ^ (l15 & 7)) << 3);   // d 32..63

  int r8 = lane >> 3;              // 0..7 (row within staging group)
  int c8 = lane & 7;
  int sw = (c8 ^ r8) * 8;          // inverse-swizzled source chunk
  const __bf16* ksrc = kb  + (size_t)r8*DHEAD + sw;
  const __bf16* vsrc = vtb + (size_t)r8*SEQ  + sw;
  int g0 = w*2, g1 = w*2 + 1;
  const size_t kg0o = (size_t)g0*8*DHEAD, kg1o = (size_t)g1*8*DHEAD;
  const size_t vg0o = (size_t)g0*8*SEQ,   vg1o = (size_t)g1*8*SEQ;

  int q0 = qi * 128;
  int nst = 2*qi + 2;                        // k-tiles of 64
  int ig0 = q0 + w*32 + l15;                 // qg=0 q-row
  int ig1 = ig0 + 16;                        // qg=1 q-row
  bf8 aq00 = *(const bf8*)(qb + (size_t)ig0*DHEAD + quad*8);
  bf8 aq01 = *(const bf8*)(qb + (size_t)ig0*DHEAD + 32 + quad*8);
  bf8 aq10 = *(const bf8*)(qb + (size_t)ig1*DHEAD + quad*8);
  bf8 aq11 = *(const bf8*)(qb + (size_t)ig1*DHEAD + 32 + quad*8);
  f4 oacc0[4] = {}, oacc1[4] = {};
  float l_0 = 0.f, l_1 = 0.f;
  glds16(ksrc + kg0o, &Ks[0][g0*512]);
  glds16(ksrc + kg1o, &Ks[0][g1*512]);
  glds16(vsrc + vg0o, &Vts[0][g0*512]);
  glds16(vsrc + vg1o, &Vts[0][g1*512]);
  __syncthreads();
  int cur = 0;
  for(int t=0; t<nst; t++){
    int j0 = t*64;
    bool pf = (t+1) < nst;
    if(pf){
      int nb = cur ^ 1;
      size_t off = (size_t)(t+1)*64;
      glds16(ksrc + off*DHEAD + kg0o, &Ks[nb][g0*512]);
      glds16(ksrc + off*DHEAD + kg1o, &Ks[nb][g1*512]);
      glds16(vsrc + vg0o + off,       &Vts[nb][g0*512]);
      glds16(vsrc + vg1o + off,       &Vts[nb][g1*512]);
    }
    const __bf16* KsC  = Ks[cur];
    const __bf16* VtsC = Vts[cur];
    f4 s0[4] = {}, s1[4] = {};
    __builtin_amdgcn_s_setprio(1);
#pragma unroll
    for(int jt=0;jt<4;jt++){
      bf8 ak0 = *(const bf8*)&KsC[(jt*16+l15)*64 + sxq0];
      bf8 ak1 = *(const bf8*)&KsC[(jt*16+l15)*64 + sxq1];
      s0[jt] = mfma16(ak0, aq00, s0[jt]);
      s0[jt] = mfma16(ak1, aq01, s0[jt]);
      s1[jt] = mfma16(ak0, aq10, s1[jt]);
      s1[jt] = mfma16(ak1, aq11, s1[jt]);
    }
    __builtin_amdgcn_s_setprio(0);
    // hoist V-frag reads (reused for both q-groups)
    bf8 bv[2][4];
#pragma unroll
    for(int jk=0;jk<2;jk++)
#pragma unroll
      for(int nd=0;nd<4;nd++)
        bv[jk][nd] = *(const bf8*)&VtsC[(nd*16+l15)*64 + (((jk*4+quad) ^ (l15&7)) << 3)];
    bool masked = (t >= nst-2);
#pragma unroll
    for(int qg=0; qg<2; qg++){
      const f4* sq = qg ? s1 : s0;
      int iq = qg ? ig1 : ig0;
      float sv[4][4];
      if(!masked){
        float cdi = c2 * (float)(iq - j0) + 8.0f;
#pragma unroll
        for(int jt=0;jt<4;jt++)
#pragma unroll
          for(int r=0;r<4;r++)
            sv[jt][r] = fmaf(sq[jt][r], c1, cjb[jt*4+r] - cdi);
      } else {
#pragma unroll
        for(int jt=0;jt<4;jt++)
#pragma unroll
          for(int r=0;r<4;r++){
            int j = j0 + jt*16 + quad*4 + r;
            int d = iq - j;
            float val = fmaf(sq[jt][r], c1, -fmaf(c2, (float)d, 8.0f));
            sv[jt][r] = (d < 0) ? -1e30f : val;
          }
      }
      float lsum = 0.f;
#pragma unroll
      for(int jt=0;jt<4;jt++){
        float p0 = __builtin_amdgcn_exp2f(sv[jt][0]);
        float p1 = __builtin_amdgcn_exp2f(sv[jt][1]);
        float p2 = __builtin_amdgcn_exp2f(sv[jt][2]);
        float p3 = __builtin_amdgcn_exp2f(sv[jt][3]);
        lsum += (p0+p1)+(p2+p3);
        uint2 pk = { pack2(p0,p1), pack2(p2,p3) };
        *(uint2*)&Ps[w][qg][l15*72 + jt*16 + quad*4] = pk;
      }
      lsum += __shfl_xor(lsum, 16);
      lsum += __shfl_xor(lsum, 32);
      if(qg) l_1 += lsum; else l_0 += lsum;
    }
    __builtin_amdgcn_s_setprio(1);
#pragma unroll
    for(int jk=0;jk<2;jk++){
      bf8 ap0 = *(const bf8*)&Ps[w][0][l15*72 + jk*32 + quad*8];
      bf8 ap1 = *(const bf8*)&Ps[w][1][l15*72 + jk*32 + quad*8];
#pragma unroll
      for(int nd=0;nd<4;nd++){
        oacc0[nd] = mfma16(ap0, bv[jk][nd], oacc0[nd]);
        oacc1[nd] = mfma16(ap1, bv[jk][nd], oacc1[nd]);
      }
    }
    __builtin_amdgcn_s_setprio(0);
    __syncthreads();
    cur ^= 1;
  }
  if(quad == 0){ Al[w][0][l15] = 1.0f / l_0; Al[w][1][l15] = 1.0f / l_1; }
  f4 linv0 = *(const f4*)&Al[w][0][quad*4];
  f4 linv1 = *(const f4*)&Al[w][1][quad*4];
#pragma unroll
  for(int nd=0;nd<4;nd++)
#pragma unroll
    for(int r=0;r<4;r++){
      int io0 = q0 + w*32 + quad*4 + r;
      Oout[((size_t)(b*SEQ + io0))*DMODEL + hh*64 + nd*16 + l15] =
          (__bf16)(oacc0[nd][r] * linv0[r]);
      Oout[((size_t)(b*SEQ + io0 + 16))*DMODEL + hh*64 + nd*16 + l15] =
          (__bf16)(oacc1[nd][r] * linv1[r]);
    }
}

extern "C" void kernel_launch(void* const* d_in, const int* in_sizes, int n_in,
                              void* d_out, int out_size, void* d_ws, size_t ws_size,
                              hipStream_t stream){
  const float* x      = (const float*)d_in[0];
  const float* gam    = (const float*)d_in[1];
  const float* bet    = (const float*)d_in[2];
  const float* w_qkv  = (const float*)d_in[3];
  const float* slopes = (const float*)d_in[22];
  const float* w_out  = (const float*)d_in[23];
  float* out = (float*)d_out;

  // 48 MB workspace, aliased by liveness (proven at 48 MB):
  // [0,8)   h -> qpost
  // [8,32)  qkv -> att [8,16), wout_bf [24,26) (after conv)
  // [32,38) wqkv_bf -> kpost [32,40) (after gemm1)
  // [40,48) vtp (written by conv directly, transposed)
  char* ws = (char*)d_ws;
  __bf16* h       = (__bf16*)(ws);
  __bf16* qpost   = (__bf16*)(ws);
  __bf16* qkv     = (__bf16*)(ws + ((size_t)8  << 20));
  __bf16* att     = (__bf16*)(ws + ((size_t)8  << 20));
  __bf16* wout_bf = (__bf16*)(ws + ((size_t)24 << 20));
  __bf16* wqkv_bf = (__bf16*)(ws + ((size_t)32 << 20));
  __bf16* kpost   = (__bf16*)(ws + ((size_t)32 << 20));
  __bf16* vtp     = (__bf16*)(ws + ((size_t)40 << 20));

  constexpr int NQKV = 3 * DMODEL * DMODEL;

  prep_kernel<<<BATCH*SEQ + NQKV/4/256, 256, 0, stream>>>(x, gam, bet, h, w_qkv, wqkv_bf);
  gemm_nt<__bf16><<<dim3(E3/128, (BATCH*SEQ)/128), 256, 0, stream>>>(
      h, wqkv_bf, qkv, BATCH*SEQ, E3, DMODEL);
  conv_kernel<<<dim3(32, 12, BATCH), 256, 0, stream>>>(qkv, qpost, kpost, vtp,
    (const float*)d_in[4],(const float*)d_in[5],(const float*)d_in[6],(const float*)d_in[7],
    (const float*)d_in[8],(const float*)d_in[9],
    (const float*)d_in[10],(const float*)d_in[11],(const float*)d_in[12],(const float*)d_in[13],
    (const float*)d_in[14],(const float*)d_in[15],
    (const float*)d_in[16],(const float*)d_in[17],(const float*)d_in[18],(const float*)d_in[19],
    (const float*)d_in[20],(const float*)d_in[21]);
  attn_kernel<<<dim3(1536), 256, 0, stream>>>(qpost, kpost, vtp, slopes, att,
                                              w_out, wout_bf);
  gemm_nt<float><<<dim3(DMODEL/128, (BATCH*SEQ)/128), 256, 0, stream>>>(
      att, wout_bf, out, BATCH*SEQ, DMODEL, DMODEL);
}

// Round 12
// 227.215 us; speedup vs baseline: 1.5037x; 1.0580x over previous
//
#include <hip/hip_runtime.h>
#include <hip/hip_bf16.h>
#include <stdint.h>

typedef __bf16 bf8 __attribute__((ext_vector_type(8)));
typedef float  f4  __attribute__((ext_vector_type(4)));

constexpr int BATCH  = 2;
constexpr int SEQ    = 2048;
constexpr int DMODEL = 1024;
constexpr int NH     = 16;
constexpr int DHEAD  = 64;
constexpr int E3     = 3072;

static __device__ __forceinline__ f4 mfma16(bf8 a, bf8 b, f4 c){
  return __builtin_amdgcn_mfma_f32_16x16x32_bf16(a, b, c, 0, 0, 0);
}
static __device__ __forceinline__ uint32_t pack2(float a, float b){
  union { __bf16 h[2]; uint32_t u; } p;
  p.h[0] = (__bf16)a; p.h[1] = (__bf16)b;
  return p.u;
}
typedef const __attribute__((address_space(1))) uint32_t g_u32;
typedef __attribute__((address_space(3))) uint32_t l_u32;
static __device__ __forceinline__ void glds16(const __bf16* g, __bf16* l){
  __builtin_amdgcn_global_load_lds((g_u32*)g, (l_u32*)l, 16, 0, 0);
}

// ---------------- fused prologue: LayerNorm + w_qkv convert ----------------
// blocks [0, 4096): LN row; blocks [4096, 7168): w_qkv fp32->bf16 (1024 elems/blk)
__global__ __launch_bounds__(256) void prep_kernel(const float* __restrict__ x,
                                                   const float* __restrict__ gam,
                                                   const float* __restrict__ bet,
                                                   __bf16* __restrict__ h,
                                                   const float* __restrict__ wq,
                                                   __bf16* __restrict__ wqb){
  int bid = blockIdx.x;
  int tid = threadIdx.x;
  if(bid >= BATCH*SEQ){
    int i = ((bid - BATCH*SEQ) * 256 + tid) * 4;
    float4 v = *(const float4*)(wq + i);
    __bf16 o[4] = {(__bf16)v.x, (__bf16)v.y, (__bf16)v.z, (__bf16)v.w};
    *(uint2*)(wqb + i) = *(const uint2*)o;
    return;
  }
  int row = bid;
  const float* xr = x + (size_t)row * DMODEL;
  float4 v = *(const float4*)(xr + tid*4);
  float s = v.x + v.y + v.z + v.w;
  float ss = v.x*v.x + v.y*v.y + v.z*v.z + v.w*v.w;
#pragma unroll
  for(int m=1;m<64;m<<=1){ s += __shfl_xor(s, m); ss += __shfl_xor(ss, m); }
  __shared__ float sm[8];
  int wid = tid >> 6;
  if((tid & 63) == 0){ sm[wid] = s; sm[4+wid] = ss; }
  __syncthreads();
  s  = sm[0]+sm[1]+sm[2]+sm[3];
  ss = sm[4]+sm[5]+sm[6]+sm[7];
  float mu  = s * (1.f/DMODEL);
  float var = ss * (1.f/DMODEL) - mu*mu;
  float r = rsqrtf(var + 1e-5f);
  float4 g = *(const float4*)(gam + tid*4);
  float4 bb = *(const float4*)(bet + tid*4);
  __bf16 o[4] = { (__bf16)((v.x-mu)*r*g.x + bb.x), (__bf16)((v.y-mu)*r*g.y + bb.y),
                  (__bf16)((v.z-mu)*r*g.z + bb.z), (__bf16)((v.w-mu)*r*g.w + bb.w) };
  *(uint2*)(h + (size_t)row*DMODEL + tid*4) = *(uint2*)o;
}

// ---------------- NT GEMM 128x128, glds staging, BK=32, DOUBLE-BUFFERED -------
// + XCD-aware block swizzle (T1): nwg%8==0 for both launches (768, 256);
//   swz=(bid&7)*(nwg/8)+(bid>>3) gives each XCD a contiguous run of tiles that
//   share the A-panel -> B re-reads become L2-local. Perf-only permutation.
template<typename CT>
__global__ __launch_bounds__(256) void gemm_nt(const __bf16* __restrict__ A,
                                               const __bf16* __restrict__ Bm,
                                               CT* __restrict__ C,
                                               int M, int Ncols, int K){
  __shared__ __align__(16) __bf16 smem[4*128*32];   // As[2] | Bs[2] (32 KB)
  __bf16* As0 = smem;
  __bf16* Bs0 = smem + 2*128*32;
  int nwgx = gridDim.x;
  int nwg  = nwgx * gridDim.y;
  int bidl = blockIdx.y * nwgx + blockIdx.x;
  int swz  = (bidl & 7) * (nwg >> 3) + (bidl >> 3);
  int m0 = (swz / nwgx) * 128, n0 = (swz % nwgx) * 128;
  int tid = threadIdx.x;
  int lane = tid & 63, wid = tid >> 6;
  int quad = lane >> 4, l15 = lane & 15;
  int wm = (wid >> 1) * 64, wn = (wid & 1) * 64;
  f4 acc[4][4] = {};
  int r0 = wid*32 + (lane >> 2);
  int cofs = (lane & 3) * 8;
  const __bf16* ag = A  + (size_t)(m0 + r0) * K + cofs;
  const __bf16* bg = Bm + (size_t)(n0 + r0) * K + cofs;
  const int d0 = (wid*32)*32, d1 = (wid*32+16)*32;
  const size_t rowskip = (size_t)16 * K;
  glds16(ag,           As0 + d0);
  glds16(ag + rowskip, As0 + d1);
  glds16(bg,           Bs0 + d0);
  glds16(bg + rowskip, Bs0 + d1);
  __syncthreads();
  int cur = 0;
  for(int k0 = 0; k0 < K; k0 += 32){
    int k1 = k0 + 32;
    if(k1 < K){
      int nb = cur ^ 1;
      glds16(ag + k1,           As0 + nb*128*32 + d0);
      glds16(ag + rowskip + k1, As0 + nb*128*32 + d1);
      glds16(bg + k1,           Bs0 + nb*128*32 + d0);
      glds16(bg + rowskip + k1, Bs0 + nb*128*32 + d1);
    }
    const __bf16* AsC = As0 + cur*128*32;
    const __bf16* BsC = Bs0 + cur*128*32;
    bf8 af[4], bfr[4];
#pragma unroll
    for(int i=0;i<4;i++){
      af[i]  = *(const bf8*)&AsC[(wm + i*16 + l15)*32 + quad*8];
      bfr[i] = *(const bf8*)&BsC[(wn + i*16 + l15)*32 + quad*8];
    }
#pragma unroll
    for(int mi=0;mi<4;mi++)
#pragma unroll
      for(int ni=0;ni<4;ni++)
        acc[mi][ni] = mfma16(af[mi], bfr[ni], acc[mi][ni]);
    __syncthreads();
    cur ^= 1;
  }
  if constexpr (sizeof(CT) == 2){
    __bf16* scr = smem;                      // [32][136] bf16 = 8.7 KB
    uint32_t* sp = (uint32_t*)smem;
#pragma unroll
    for(int qq=0; qq<4; qq++){
      __syncthreads();
      if((wid>>1) == (qq>>1)){
        int mi0 = (qq & 1) * 2;
#pragma unroll
        for(int mm=0; mm<2; mm++){
          int mi = mi0 + mm;
#pragma unroll
          for(int ni=0; ni<4; ni++)
#pragma unroll
            for(int r=0; r<4; r++){
              int lr = (mi - mi0)*16 + quad*4 + r;   // 0..31
              scr[lr*136 + wn + ni*16 + l15] = (__bf16)acc[mi][ni][r];
            }
        }
      }
      __syncthreads();
#pragma unroll
      for(int it=0; it<2; it++){
        int idx = it*256 + tid;              // 0..511
        int row = idx >> 4;                  // 0..31
        int ck  = idx & 15;                  // 16B chunk
        uint4 v = { sp[row*68 + ck*4 + 0], sp[row*68 + ck*4 + 1],
                    sp[row*68 + ck*4 + 2], sp[row*68 + ck*4 + 3] };
        *(uint4*)(C + (size_t)(m0 + qq*32 + row)*Ncols + n0 + ck*8) = v;
      }
    }
  } else {
    float* scr = (float*)smem;               // [32][136] f32 = 17.4 KB (< 32 KB)
#pragma unroll
    for(int qq=0; qq<4; qq++){
      __syncthreads();
      if((wid>>1) == (qq>>1)){
        int mi0 = (qq & 1) * 2;
#pragma unroll
        for(int mm=0; mm<2; mm++){
          int mi = mi0 + mm;
#pragma unroll
          for(int ni=0; ni<4; ni++)
#pragma unroll
            for(int r=0; r<4; r++){
              int lr = (mi - mi0)*16 + quad*4 + r;   // 0..31
              scr[lr*136 + wn + ni*16 + l15] = acc[mi][ni][r];
            }
        }
      }
      __syncthreads();
#pragma unroll
      for(int it=0; it<4; it++){
        int idx = it*256 + tid;              // 0..1023
        int row = idx >> 5;                  // 0..31
        int ck  = idx & 31;                  // 16B chunk (4 f32)
        float4 v = { scr[row*136 + ck*4 + 0], scr[row*136 + ck*4 + 1],
                     scr[row*136 + ck*4 + 2], scr[row*136 + ck*4 + 3] };
        *(float4*)(C + (size_t)(m0 + qq*32 + row)*Ncols + n0 + ck*4) = v;
      }
    }
  }
}

// ---------------- grouped depthwise causal conv, LDS-tiled input ----------------
// (R9 scratch-fix version: block-uniform weight select, named registers)
__global__ __launch_bounds__(256) void conv_kernel(const __bf16* __restrict__ qkv,
    __bf16* __restrict__ qo, __bf16* __restrict__ ko, __bf16* __restrict__ vt,
    const float* qw3,const float* qb3,const float* qw5,const float* qb5,const float* qw7,const float* qb7,
    const float* kw3,const float* kb3,const float* kw5,const float* kb5,const float* kw7,const float* kb7,
    const float* vw3,const float* vb3,const float* vw5,const float* vb5,const float* vw7,const float* vb7){
  __shared__ __align__(16) __bf16 tile[72*256];   // rows: n0-8 .. n0+63
  int nc = blockIdx.x;      // 32 chunks of 64 along N
  int ec = blockIdx.y;      // 12 chunks of 256 channels
  int b  = blockIdx.z;
  int tid = threadIdx.x;
  int n0 = nc * 64;
  {
    int rrow = tid >> 5;          // 0..7
    int ccol = (tid & 31) * 8;    // 0..248
    const __bf16* src = qkv + (size_t)b*SEQ*E3 + ec*256 + ccol;
#pragma unroll
    for(int p=0;p<9;p++){
      int row = p*8 + rrow;
      int n = n0 - 8 + row;
      uint4 v = {0u,0u,0u,0u};
      if(n >= 0) v = *(const uint4*)(src + (size_t)n*E3);
      *(uint4*)&tile[row*256 + ccol] = v;
    }
  }
  __syncthreads();
  int p = ec >> 2;          // 0=Q, 1=K, 2=V   (block-uniform)
  int g = ec & 3;           // 0=id, 1=k3, 2=k5, 3=k7   (block-uniform)
  float w0=0.f,w1=0.f,w2=0.f,w3=0.f,w4=0.f,w5=0.f,w6=0.f,bias=0.f;
  if(g == 1){
    const float* wp = (p==0)? qw3 : (p==1)? kw3 : vw3;
    const float* bp = (p==0)? qb3 : (p==1)? kb3 : vb3;
    w0 = wp[tid*3+0]; w1 = wp[tid*3+1]; w2 = wp[tid*3+2]; bias = bp[tid];
  } else if(g == 2){
    const float* wp = (p==0)? qw5 : (p==1)? kw5 : vw5;
    const float* bp = (p==0)? qb5 : (p==1)? kb5 : vb5;
    w0 = wp[tid*5+0]; w1 = wp[tid*5+1]; w2 = wp[tid*5+2];
    w3 = wp[tid*5+3]; w4 = wp[tid*5+4]; bias = bp[tid];
  } else if(g == 3){
    const float* wp = (p==0)? qw7 : (p==1)? kw7 : vw7;
    const float* bp = (p==0)? qb7 : (p==1)? kb7 : vb7;
    w0 = wp[tid*7+0]; w1 = wp[tid*7+1]; w2 = wp[tid*7+2]; w3 = wp[tid*7+3];
    w4 = wp[tid*7+4]; w5 = wp[tid*7+5]; w6 = wp[tid*7+6]; bias = bp[tid];
  }
  float x0 = (float)tile[2*256 + tid];
  float x1 = (float)tile[3*256 + tid];
  float x2 = (float)tile[4*256 + tid];
  float x3 = (float)tile[5*256 + tid];
  float x4 = (float)tile[6*256 + tid];
  float x5 = (float)tile[7*256 + tid];
#define CONV_STEP(cur, o)                                                      \
  { if(g == 0)      o = (cur);                                                 \
    else if(g == 1) o = w0*x4 + w1*x5 + w2*(cur) + bias;                       \
    else if(g == 2) o = w0*x2 + w1*x3 + w2*x4 + w3*x5 + w4*(cur) + bias;       \
    else            o = w0*x0 + w1*x1 + w2*x2 + w3*x3 + w4*x4 + w5*x5          \
                        + w6*(cur) + bias;                                     \
    x0=x1; x1=x2; x2=x3; x3=x4; x4=x5; x5=(cur); }
  if(p == 2){
    uint32_t vout[32];
#pragma unroll
    for(int blk=0; blk<8; blk++){
#pragma unroll
      for(int up=0; up<4; up++){
        float ca = (float)tile[(8 + blk*8 + up*2    )*256 + tid];
        float oa; CONV_STEP(ca, oa);
        float cb = (float)tile[(8 + blk*8 + up*2 + 1)*256 + tid];
        float ob; CONV_STEP(cb, ob);
        vout[blk*4 + up] = pack2(oa, ob);
      }
    }
    __syncthreads();                         // all tile reads done
    uint32_t* ot = (uint32_t*)tile;          // reuse as [256 ch][33 u32] (padded)
#pragma unroll
    for(int j=0;j<32;j++) ot[tid*33 + j] = vout[j];
    __syncthreads();
#pragma unroll
    for(int it=0; it<8; it++){
      int idx = it*256 + tid;                // 0..2047
      int ch  = idx >> 3;                    // local channel 0..255
      int ncq = idx & 7;                     // 16B chunk along n
      uint4 val = { ot[ch*33 + ncq*4 + 0], ot[ch*33 + ncq*4 + 1],
                    ot[ch*33 + ncq*4 + 2], ot[ch*33 + ncq*4 + 3] };
      int hh2 = g*4 + (ch >> 6);
      int dh2 = ch & 63;
      *(uint4*)(vt + ((size_t)((b*NH + hh2)*DHEAD + dh2))*SEQ + n0 + ncq*8) = val;
    }
  } else {
    int hh = g*4 + (tid >> 6);
    int dh = tid & 63;
    __bf16* outp = (p==0) ? qo : ko;
    __bf16* op = outp + ((size_t)(b*NH + hh)*SEQ)*DHEAD + dh;
#pragma unroll 8
    for(int dn=0; dn<64; dn++){
      float cur = (float)tile[(8+dn)*256 + tid];
      float o; CONV_STEP(cur, o);
      op[(size_t)(n0+dn)*DHEAD] = (__bf16)o;
    }
  }
#undef CONV_STEP
}

// ---------------- flash attention + fused w_out convert ----------------
// R9 build (session-best attn: 43.4 us): KVBLK=64 dbuf, 4-wave blocks,
// LDS 41.5 KB -> 3 blocks/CU. Grid: 1024 attn blocks, one 64-row q-tile each,
// longest-first (qi = 31 - bid>>5); XCD pin bid&7 == head&7.
// Blocks [1024,2048): w_out fp32->bf16.
// (R10/R11's QBLK=128 K/V-reuse variant was falsified: spill-fixed version
//  still 54 us — occupancy loss beats the -36% DS-op saving. Reverted.)
__global__ __launch_bounds__(256, 3) void attn_kernel(const __bf16* __restrict__ Qin,
                                                      const __bf16* __restrict__ Kin,
                                                      const __bf16* __restrict__ Vtin,
                                                      const float* __restrict__ slopes,
                                                      __bf16* __restrict__ Oout,
                                                      const float* __restrict__ wsrc,
                                                      __bf16* __restrict__ wdst){
  __shared__ __align__(16) __bf16 Ks[2][64*64];     // K tile: 64 k-rows x 64 d
  __shared__ __align__(16) __bf16 Vts[2][64*64];    // V^T tile: 64 d x 64 n
  __shared__ __align__(16) __bf16 Ps[4][16*72];
  __shared__ float Al[4][16];
  int bid = blockIdx.x;
  int tid = threadIdx.x;
  if(bid >= 1024){
    int i = ((bid - 1024) * 256 + tid) * 4;
    float4 v = *(const float4*)(wsrc + i);
    __bf16 o[4] = {(__bf16)v.x, (__bf16)v.y, (__bf16)v.z, (__bf16)v.w};
    *(uint2*)(wdst + i) = *(const uint2*)o;
    return;
  }
  int qi = 31 - (bid >> 5);                       // q-tile, longest first
  int by = (bid & 7) + ((bid >> 3) & 3) * 8;      // 0..31, by%8 == bid%8 (XCD pin)
  int b  = by >> 4, hh = by & 15;
  int lane = tid & 63, w = tid >> 6;
  int quad = lane >> 4, l15 = lane & 15;
  const __bf16* qb  = Qin  + (size_t)by * SEQ * DHEAD;
  const __bf16* kb  = Kin  + (size_t)by * SEQ * DHEAD;
  const __bf16* vtb = Vtin + (size_t)by * DHEAD * SEQ;
  const float L2E = 1.4426950408889634f;
  float slope = slopes[hh];
  const float c1 = 0.125f * L2E;
  float c2 = slope * L2E;
  float cjb[16];
#pragma unroll
  for(int jt=0;jt<4;jt++)
#pragma unroll
    for(int r=0;r<4;r++)
      cjb[jt*4+r] = c2 * (float)(jt*16 + quad*4 + r);

  int sxq0 = ((quad     ^ (l15 & 7)) << 3);   // d 0..31
  int sxq1 = (((quad+4) ^ (l15 & 7)) << 3);   // d 32..63

  int r8 = lane >> 3;              // 0..7 (row within group)
  int c8 = lane & 7;
  int sw = (c8 ^ r8) * 8;          // inverse-swizzled source chunk
  const __bf16* ksrc = kb  + (size_t)r8*DHEAD + sw;
  const __bf16* vsrc = vtb + (size_t)r8*SEQ  + sw;
  int g0 = w*2, g1 = w*2 + 1;
  const size_t kg0o = (size_t)g0*8*DHEAD, kg1o = (size_t)g1*8*DHEAD;
  const size_t vg0o = (size_t)g0*8*SEQ,   vg1o = (size_t)g1*8*SEQ;

  int q0 = qi * 64;
  int nst = qi + 1;                          // k-tiles of 64
  int i0 = q0 + w*16;
  int i  = i0 + l15;
  bf8 aq0 = *(const bf8*)(qb + (size_t)i*DHEAD + quad*8);
  bf8 aq1 = *(const bf8*)(qb + (size_t)i*DHEAD + 32 + quad*8);
  f4 oacc[4] = {};
  float l_ = 0.f;
  glds16(ksrc + kg0o, &Ks[0][g0*512]);
  glds16(ksrc + kg1o, &Ks[0][g1*512]);
  glds16(vsrc + vg0o, &Vts[0][g0*512]);
  glds16(vsrc + vg1o, &Vts[0][g1*512]);
  __syncthreads();
  int cur = 0;
  for(int t=0; t<nst; t++){
    int j0 = t*64;
    bool pf = (t+1) < nst;
    if(pf){
      int nb = cur ^ 1;
      size_t off = (size_t)(t+1)*64;
      glds16(ksrc + off*DHEAD + kg0o, &Ks[nb][g0*512]);
      glds16(ksrc + off*DHEAD + kg1o, &Ks[nb][g1*512]);
      glds16(vsrc + vg0o + off,       &Vts[nb][g0*512]);
      glds16(vsrc + vg1o + off,       &Vts[nb][g1*512]);
    }
    const __bf16* KsC  = Ks[cur];
    const __bf16* VtsC = Vts[cur];
    f4 s[4] = {};
    __builtin_amdgcn_s_setprio(1);
#pragma unroll
    for(int jt=0;jt<4;jt++){
      bf8 ak0 = *(const bf8*)&KsC[(jt*16+l15)*64 + sxq0];
      bf8 ak1 = *(const bf8*)&KsC[(jt*16+l15)*64 + sxq1];
      s[jt] = mfma16(ak0, aq0, s[jt]);
      s[jt] = mfma16(ak1, aq1, s[jt]);
    }
    __builtin_amdgcn_s_setprio(0);
    bf8 bv[2][4];
#pragma unroll
    for(int jk=0;jk<2;jk++)
#pragma unroll
      for(int nd=0;nd<4;nd++)
        bv[jk][nd] = *(const bf8*)&VtsC[(nd*16+l15)*64 + (((jk*4+quad) ^ (l15&7)) << 3)];
    float sv[4][4];
    if(t < nst-1){
      float cdi = c2 * (float)(i - j0) + 8.0f;
#pragma unroll
      for(int jt=0;jt<4;jt++)
#pragma unroll
        for(int r=0;r<4;r++)
          sv[jt][r] = fmaf(s[jt][r], c1, cjb[jt*4+r] - cdi);
    } else {
#pragma unroll
      for(int jt=0;jt<4;jt++)
#pragma unroll
        for(int r=0;r<4;r++){
          int j = j0 + jt*16 + quad*4 + r;
          int d = i - j;
          float val = fmaf(s[jt][r], c1, -fmaf(c2, (float)d, 8.0f));
          sv[jt][r] = (d < 0) ? -1e30f : val;
        }
    }
    float lsum = 0.f;
#pragma unroll
    for(int jt=0;jt<4;jt++){
      float p0 = __builtin_amdgcn_exp2f(sv[jt][0]);
      float p1 = __builtin_amdgcn_exp2f(sv[jt][1]);
      float p2 = __builtin_amdgcn_exp2f(sv[jt][2]);
      float p3 = __builtin_amdgcn_exp2f(sv[jt][3]);
      lsum += (p0+p1)+(p2+p3);
      uint2 pk = { pack2(p0,p1), pack2(p2,p3) };
      *(uint2*)&Ps[w][l15*72 + jt*16 + quad*4] = pk;
    }
    lsum += __shfl_xor(lsum, 16);
    lsum += __shfl_xor(lsum, 32);
    l_ += lsum;
    __builtin_amdgcn_s_setprio(1);
#pragma unroll
    for(int jk=0;jk<2;jk++){
      bf8 ap = *(const bf8*)&Ps[w][l15*72 + jk*32 + quad*8];
#pragma unroll
      for(int nd=0;nd<4;nd++)
        oacc[nd] = mfma16(ap, bv[jk][nd], oacc[nd]);
    }
    __builtin_amdgcn_s_setprio(0);
    __syncthreads();
    cur ^= 1;
  }
  if(quad == 0) Al[w][l15] = 1.0f / l_;
  f4 linv = *(const f4*)&Al[w][quad*4];
#pragma unroll
  for(int nd=0;nd<4;nd++)
#pragma unroll
    for(int r=0;r<4;r++){
      int io = i0 + quad*4 + r;
      Oout[((size_t)(b*SEQ + io))*DMODEL + hh*64 + nd*16 + l15] =
          (__bf16)(oacc[nd][r] * linv[r]);
    }
}

extern "C" void kernel_launch(void* const* d_in, const int* in_sizes, int n_in,
                              void* d_out, int out_size, void* d_ws, size_t ws_size,
                              hipStream_t stream){
  const float* x      = (const float*)d_in[0];
  const float* gam    = (const float*)d_in[1];
  const float* bet    = (const float*)d_in[2];
  const float* w_qkv  = (const float*)d_in[3];
  const float* slopes = (const float*)d_in[22];
  const float* w_out  = (const float*)d_in[23];
  float* out = (float*)d_out;

  // 48 MB workspace, aliased by liveness (proven at 48 MB):
  // [0,8)   h -> qpost
  // [8,32)  qkv -> att [8,16), wout_bf [24,26) (after conv)
  // [32,38) wqkv_bf -> kpost [32,40) (after gemm1)
  // [40,48) vtp (written by conv directly, transposed)
  char* ws = (char*)d_ws;
  __bf16* h       = (__bf16*)(ws);
  __bf16* qpost   = (__bf16*)(ws);
  __bf16* qkv     = (__bf16*)(ws + ((size_t)8  << 20));
  __bf16* att     = (__bf16*)(ws + ((size_t)8  << 20));
  __bf16* wout_bf = (__bf16*)(ws + ((size_t)24 << 20));
  __bf16* wqkv_bf = (__bf16*)(ws + ((size_t)32 << 20));
  __bf16* kpost   = (__bf16*)(ws + ((size_t)32 << 20));
  __bf16* vtp     = (__bf16*)(ws + ((size_t)40 << 20));

  constexpr int NQKV = 3 * DMODEL * DMODEL;

  prep_kernel<<<BATCH*SEQ + NQKV/4/256, 256, 0, stream>>>(x, gam, bet, h, w_qkv, wqkv_bf);
  gemm_nt<__bf16><<<dim3(E3/128, (BATCH*SEQ)/128), 256, 0, stream>>>(
      h, wqkv_bf, qkv, BATCH*SEQ, E3, DMODEL);
  conv_kernel<<<dim3(32, 12, BATCH), 256, 0, stream>>>(qkv, qpost, kpost, vtp,
    (const float*)d_in[4],(const float*)d_in[5],(const float*)d_in[6],(const float*)d_in[7],
    (const float*)d_in[8],(const float*)d_in[9],
    (const float*)d_in[10],(const float*)d_in[11],(const float*)d_in[12],(const float*)d_in[13],
    (const float*)d_in[14],(const float*)d_in[15],
    (const float*)d_in[16],(const float*)d_in[17],(const float*)d_in[18],(const float*)d_in[19],
    (const float*)d_in[20],(const float*)d_in[21]);
  attn_kernel<<<dim3(2048), 256, 0, stream>>>(qpost, kpost, vtp, slopes, att,
                                              w_out, wout_bf);
  gemm_nt<float><<<dim3(DMODEL/128, (BATCH*SEQ)/128), 256, 0, stream>>>(
      att, wout_bf, out, BATCH*SEQ, DMODEL, DMODEL);
}

// Round 13
// 225.492 us; speedup vs baseline: 1.5152x; 1.0076x over previous
//
#include <hip/hip_runtime.h>
#include <hip/hip_bf16.h>
#include <stdint.h>

typedef __bf16 bf8 __attribute__((ext_vector_type(8)));
typedef float  f4  __attribute__((ext_vector_type(4)));

constexpr int BATCH  = 2;
constexpr int SEQ    = 2048;
constexpr int DMODEL = 1024;
constexpr int NH     = 16;
constexpr int DHEAD  = 64;
constexpr int E3     = 3072;

static __device__ __forceinline__ f4 mfma16(bf8 a, bf8 b, f4 c){
  return __builtin_amdgcn_mfma_f32_16x16x32_bf16(a, b, c, 0, 0, 0);
}
static __device__ __forceinline__ uint32_t pack2(float a, float b){
  union { __bf16 h[2]; uint32_t u; } p;
  p.h[0] = (__bf16)a; p.h[1] = (__bf16)b;
  return p.u;
}
typedef const __attribute__((address_space(1))) uint32_t g_u32;
typedef __attribute__((address_space(3))) uint32_t l_u32;
static __device__ __forceinline__ void glds16(const __bf16* g, __bf16* l){
  __builtin_amdgcn_global_load_lds((g_u32*)g, (l_u32*)l, 16, 0, 0);
}

// ---------------- fused prologue: LayerNorm + w_qkv convert ----------------
// blocks [0, 4096): LN row; blocks [4096, 7168): w_qkv fp32->bf16 (1024 elems/blk)
__global__ __launch_bounds__(256) void prep_kernel(const float* __restrict__ x,
                                                   const float* __restrict__ gam,
                                                   const float* __restrict__ bet,
                                                   __bf16* __restrict__ h,
                                                   const float* __restrict__ wq,
                                                   __bf16* __restrict__ wqb){
  int bid = blockIdx.x;
  int tid = threadIdx.x;
  if(bid >= BATCH*SEQ){
    int i = ((bid - BATCH*SEQ) * 256 + tid) * 4;
    float4 v = *(const float4*)(wq + i);
    __bf16 o[4] = {(__bf16)v.x, (__bf16)v.y, (__bf16)v.z, (__bf16)v.w};
    *(uint2*)(wqb + i) = *(const uint2*)o;
    return;
  }
  int row = bid;
  const float* xr = x + (size_t)row * DMODEL;
  float4 v = *(const float4*)(xr + tid*4);
  float s = v.x + v.y + v.z + v.w;
  float ss = v.x*v.x + v.y*v.y + v.z*v.z + v.w*v.w;
#pragma unroll
  for(int m=1;m<64;m<<=1){ s += __shfl_xor(s, m); ss += __shfl_xor(ss, m); }
  __shared__ float sm[8];
  int wid = tid >> 6;
  if((tid & 63) == 0){ sm[wid] = s; sm[4+wid] = ss; }
  __syncthreads();
  s  = sm[0]+sm[1]+sm[2]+sm[3];
  ss = sm[4]+sm[5]+sm[6]+sm[7];
  float mu  = s * (1.f/DMODEL);
  float var = ss * (1.f/DMODEL) - mu*mu;
  float r = rsqrtf(var + 1e-5f);
  float4 g = *(const float4*)(gam + tid*4);
  float4 bb = *(const float4*)(bet + tid*4);
  __bf16 o[4] = { (__bf16)((v.x-mu)*r*g.x + bb.x), (__bf16)((v.y-mu)*r*g.y + bb.y),
                  (__bf16)((v.z-mu)*r*g.z + bb.z), (__bf16)((v.w-mu)*r*g.w + bb.w) };
  *(uint2*)(h + (size_t)row*DMODEL + tid*4) = *(uint2*)o;
}

// ---------------- NT GEMM 128x128, glds staging, BK=32, DOUBLE-BUFFERED -------
// + XCD-aware block swizzle (T1): nwg%8==0 for both launches (768, 256).
template<typename CT>
__global__ __launch_bounds__(256) void gemm_nt(const __bf16* __restrict__ A,
                                               const __bf16* __restrict__ Bm,
                                               CT* __restrict__ C,
                                               int M, int Ncols, int K){
  __shared__ __align__(16) __bf16 smem[4*128*32];   // As[2] | Bs[2] (32 KB)
  __bf16* As0 = smem;
  __bf16* Bs0 = smem + 2*128*32;
  int nwgx = gridDim.x;
  int nwg  = nwgx * gridDim.y;
  int bidl = blockIdx.y * nwgx + blockIdx.x;
  int swz  = (bidl & 7) * (nwg >> 3) + (bidl >> 3);
  int m0 = (swz / nwgx) * 128, n0 = (swz % nwgx) * 128;
  int tid = threadIdx.x;
  int lane = tid & 63, wid = tid >> 6;
  int quad = lane >> 4, l15 = lane & 15;
  int wm = (wid >> 1) * 64, wn = (wid & 1) * 64;
  f4 acc[4][4] = {};
  int r0 = wid*32 + (lane >> 2);
  int cofs = (lane & 3) * 8;
  const __bf16* ag = A  + (size_t)(m0 + r0) * K + cofs;
  const __bf16* bg = Bm + (size_t)(n0 + r0) * K + cofs;
  const int d0 = (wid*32)*32, d1 = (wid*32+16)*32;
  const size_t rowskip = (size_t)16 * K;
  glds16(ag,           As0 + d0);
  glds16(ag + rowskip, As0 + d1);
  glds16(bg,           Bs0 + d0);
  glds16(bg + rowskip, Bs0 + d1);
  __syncthreads();
  int cur = 0;
  for(int k0 = 0; k0 < K; k0 += 32){
    int k1 = k0 + 32;
    if(k1 < K){
      int nb = cur ^ 1;
      glds16(ag + k1,           As0 + nb*128*32 + d0);
      glds16(ag + rowskip + k1, As0 + nb*128*32 + d1);
      glds16(bg + k1,           Bs0 + nb*128*32 + d0);
      glds16(bg + rowskip + k1, Bs0 + nb*128*32 + d1);
    }
    const __bf16* AsC = As0 + cur*128*32;
    const __bf16* BsC = Bs0 + cur*128*32;
    bf8 af[4], bfr[4];
#pragma unroll
    for(int i=0;i<4;i++){
      af[i]  = *(const bf8*)&AsC[(wm + i*16 + l15)*32 + quad*8];
      bfr[i] = *(const bf8*)&BsC[(wn + i*16 + l15)*32 + quad*8];
    }
#pragma unroll
    for(int mi=0;mi<4;mi++)
#pragma unroll
      for(int ni=0;ni<4;ni++)
        acc[mi][ni] = mfma16(af[mi], bfr[ni], acc[mi][ni]);
    __syncthreads();
    cur ^= 1;
  }
  if constexpr (sizeof(CT) == 2){
    __bf16* scr = smem;                      // [32][136] bf16 = 8.7 KB
    uint32_t* sp = (uint32_t*)smem;
#pragma unroll
    for(int qq=0; qq<4; qq++){
      __syncthreads();
      if((wid>>1) == (qq>>1)){
        int mi0 = (qq & 1) * 2;
#pragma unroll
        for(int mm=0; mm<2; mm++){
          int mi = mi0 + mm;
#pragma unroll
          for(int ni=0; ni<4; ni++)
#pragma unroll
            for(int r=0; r<4; r++){
              int lr = (mi - mi0)*16 + quad*4 + r;   // 0..31
              scr[lr*136 + wn + ni*16 + l15] = (__bf16)acc[mi][ni][r];
            }
        }
      }
      __syncthreads();
#pragma unroll
      for(int it=0; it<2; it++){
        int idx = it*256 + tid;              // 0..511
        int row = idx >> 4;                  // 0..31
        int ck  = idx & 15;                  // 16B chunk
        uint4 v = { sp[row*68 + ck*4 + 0], sp[row*68 + ck*4 + 1],
                    sp[row*68 + ck*4 + 2], sp[row*68 + ck*4 + 3] };
        *(uint4*)(C + (size_t)(m0 + qq*32 + row)*Ncols + n0 + ck*8) = v;
      }
    }
  } else {
    float* scr = (float*)smem;               // [32][136] f32 = 17.4 KB (< 32 KB)
#pragma unroll
    for(int qq=0; qq<4; qq++){
      __syncthreads();
      if((wid>>1) == (qq>>1)){
        int mi0 = (qq & 1) * 2;
#pragma unroll
        for(int mm=0; mm<2; mm++){
          int mi = mi0 + mm;
#pragma unroll
          for(int ni=0; ni<4; ni++)
#pragma unroll
            for(int r=0; r<4; r++){
              int lr = (mi - mi0)*16 + quad*4 + r;   // 0..31
              scr[lr*136 + wn + ni*16 + l15] = acc[mi][ni][r];
            }
        }
      }
      __syncthreads();
#pragma unroll
      for(int it=0; it<4; it++){
        int idx = it*256 + tid;              // 0..1023
        int row = idx >> 5;                  // 0..31
        int ck  = idx & 31;                  // 16B chunk (4 f32)
        float4 v = { scr[row*136 + ck*4 + 0], scr[row*136 + ck*4 + 1],
                     scr[row*136 + ck*4 + 2], scr[row*136 + ck*4 + 3] };
        *(float4*)(C + (size_t)(m0 + qq*32 + row)*Ncols + n0 + ck*4) = v;
      }
    }
  }
}

// ---------------- grouped depthwise causal conv, LDS-tiled input ----------------
// R9 scratch-fix (block-uniform weight select, named registers) +
// R13: Q/K stores now ALSO go through the LDS transpose (like V since R4):
// 64 scalar 2B stores/thread (128B per wave-inst) -> 8 uint4 stores/thread,
// each wave-inst writing 1 KB fully contiguous ((n,dh) row-major: lanes cover
// dh 0..63 x 8 consecutive n).
__global__ __launch_bounds__(256) void conv_kernel(const __bf16* __restrict__ qkv,
    __bf16* __restrict__ qo, __bf16* __restrict__ ko, __bf16* __restrict__ vt,
    const float* qw3,const float* qb3,const float* qw5,const float* qb5,const float* qw7,const float* qb7,
    const float* kw3,const float* kb3,const float* kw5,const float* kb5,const float* kw7,const float* kb7,
    const float* vw3,const float* vb3,const float* vw5,const float* vb5,const float* vw7,const float* vb7){
  __shared__ __align__(16) __bf16 tile[72*256];   // rows: n0-8 .. n0+63
  int nc = blockIdx.x;      // 32 chunks of 64 along N
  int ec = blockIdx.y;      // 12 chunks of 256 channels
  int b  = blockIdx.z;
  int tid = threadIdx.x;
  int n0 = nc * 64;
  {
    int rrow = tid >> 5;          // 0..7
    int ccol = (tid & 31) * 8;    // 0..248
    const __bf16* src = qkv + (size_t)b*SEQ*E3 + ec*256 + ccol;
#pragma unroll
    for(int p=0;p<9;p++){
      int row = p*8 + rrow;
      int n = n0 - 8 + row;
      uint4 v = {0u,0u,0u,0u};
      if(n >= 0) v = *(const uint4*)(src + (size_t)n*E3);
      *(uint4*)&tile[row*256 + ccol] = v;
    }
  }
  __syncthreads();
  int p = ec >> 2;          // 0=Q, 1=K, 2=V   (block-uniform)
  int g = ec & 3;           // 0=id, 1=k3, 2=k5, 3=k7   (block-uniform)
  float w0=0.f,w1=0.f,w2=0.f,w3=0.f,w4=0.f,w5=0.f,w6=0.f,bias=0.f;
  if(g == 1){
    const float* wp = (p==0)? qw3 : (p==1)? kw3 : vw3;
    const float* bp = (p==0)? qb3 : (p==1)? kb3 : vb3;
    w0 = wp[tid*3+0]; w1 = wp[tid*3+1]; w2 = wp[tid*3+2]; bias = bp[tid];
  } else if(g == 2){
    const float* wp = (p==0)? qw5 : (p==1)? kw5 : vw5;
    const float* bp = (p==0)? qb5 : (p==1)? kb5 : vb5;
    w0 = wp[tid*5+0]; w1 = wp[tid*5+1]; w2 = wp[tid*5+2];
    w3 = wp[tid*5+3]; w4 = wp[tid*5+4]; bias = bp[tid];
  } else if(g == 3){
    const float* wp = (p==0)? qw7 : (p==1)? kw7 : vw7;
    const float* bp = (p==0)? qb7 : (p==1)? kb7 : vb7;
    w0 = wp[tid*7+0]; w1 = wp[tid*7+1]; w2 = wp[tid*7+2]; w3 = wp[tid*7+3];
    w4 = wp[tid*7+4]; w5 = wp[tid*7+5]; w6 = wp[tid*7+6]; bias = bp[tid];
  }
  float x0 = (float)tile[2*256 + tid];
  float x1 = (float)tile[3*256 + tid];
  float x2 = (float)tile[4*256 + tid];
  float x3 = (float)tile[5*256 + tid];
  float x4 = (float)tile[6*256 + tid];
  float x5 = (float)tile[7*256 + tid];
#define CONV_STEP(cur, o)                                                      \
  { if(g == 0)      o = (cur);                                                 \
    else if(g == 1) o = w0*x4 + w1*x5 + w2*(cur) + bias;                       \
    else if(g == 2) o = w0*x2 + w1*x3 + w2*x4 + w3*x5 + w4*(cur) + bias;       \
    else            o = w0*x0 + w1*x1 + w2*x2 + w3*x3 + w4*x4 + w5*x5          \
                        + w6*(cur) + bias;                                     \
    x0=x1; x1=x2; x2=x3; x3=x4; x4=x5; x5=(cur); }
  // compute all 64 outputs into regs as packed bf16 pairs (constant-indexed)
  uint32_t vout[32];
#pragma unroll
  for(int blk=0; blk<8; blk++){
#pragma unroll
    for(int up=0; up<4; up++){
      float ca = (float)tile[(8 + blk*8 + up*2    )*256 + tid];
      float oa; CONV_STEP(ca, oa);
      float cb = (float)tile[(8 + blk*8 + up*2 + 1)*256 + tid];
      float ob; CONV_STEP(cb, ob);
      vout[blk*4 + up] = pack2(oa, ob);
    }
  }
#undef CONV_STEP
  __syncthreads();                         // all tile reads done
  uint32_t* ot = (uint32_t*)tile;          // reuse as [256 ch][33 u32] (padded)
#pragma unroll
  for(int j=0;j<32;j++) ot[tid*33 + j] = vout[j];
  __syncthreads();
  if(p == 2){
    // V: transposed output (b,hh,dh,n): uint4 runs along n
#pragma unroll
    for(int it=0; it<8; it++){
      int idx = it*256 + tid;                // 0..2047
      int ch  = idx >> 3;                    // local channel 0..255
      int ncq = idx & 7;                     // 16B chunk along n
      uint4 val = { ot[ch*33 + ncq*4 + 0], ot[ch*33 + ncq*4 + 1],
                    ot[ch*33 + ncq*4 + 2], ot[ch*33 + ncq*4 + 3] };
      int hh2 = g*4 + (ch >> 6);
      int dh2 = ch & 63;
      *(uint4*)(vt + ((size_t)((b*NH + hh2)*DHEAD + dh2))*SEQ + n0 + ncq*8) = val;
    }
  } else {
    // Q/K: (b,hh,n,dh) layout: gather 8 dh (8 ch rows) at fixed n -> uint4;
    // wave writes 1 KB contiguous (lanes: ck 0..7 x consecutive n).
    __bf16* outp = (p==0) ? qo : ko;
#pragma unroll
    for(int it=0; it<8; it++){
      int idx = it*256 + tid;                // 0..2047
      int lh  = idx >> 9;                    // local head 0..3
      int dn  = (idx >> 3) & 63;             // n offset 0..63
      int ck  = idx & 7;                     // dh chunk (8 bf16)
      int j   = dn >> 1;
      int sh  = (dn & 1) * 16;
      uint32_t hv[8];
#pragma unroll
      for(int m=0;m<8;m++)
        hv[m] = (ot[(lh*64 + ck*8 + m)*33 + j] >> sh) & 0xffffu;
      uint4 val = { hv[0] | (hv[1]<<16), hv[2] | (hv[3]<<16),
                    hv[4] | (hv[5]<<16), hv[6] | (hv[7]<<16) };
      int hh2 = g*4 + lh;
      *(uint4*)(outp + ((size_t)(b*NH + hh2)*SEQ + n0 + dn)*DHEAD + ck*8) = val;
    }
  }
}

// ---------------- flash attention + fused w_out convert ----------------
// R9 build (session-best attn): KVBLK=64 dbuf, 4-wave blocks, LDS 41.5 KB ->
// 3 blocks/CU. Grid: 1024 attn blocks, longest-first; XCD pin bid&7 == head&7.
// Blocks [1024,2048): w_out fp32->bf16.
__global__ __launch_bounds__(256, 3) void attn_kernel(const __bf16* __restrict__ Qin,
                                                      const __bf16* __restrict__ Kin,
                                                      const __bf16* __restrict__ Vtin,
                                                      const float* __restrict__ slopes,
                                                      __bf16* __restrict__ Oout,
                                                      const float* __restrict__ wsrc,
                                                      __bf16* __restrict__ wdst){
  __shared__ __align__(16) __bf16 Ks[2][64*64];     // K tile: 64 k-rows x 64 d
  __shared__ __align__(16) __bf16 Vts[2][64*64];    // V^T tile: 64 d x 64 n
  __shared__ __align__(16) __bf16 Ps[4][16*72];
  __shared__ float Al[4][16];
  int bid = blockIdx.x;
  int tid = threadIdx.x;
  if(bid >= 1024){
    int i = ((bid - 1024) * 256 + tid) * 4;
    float4 v = *(const float4*)(wsrc + i);
    __bf16 o[4] = {(__bf16)v.x, (__bf16)v.y, (__bf16)v.z, (__bf16)v.w};
    *(uint2*)(wdst + i) = *(const uint2*)o;
    return;
  }
  int qi = 31 - (bid >> 5);                       // q-tile, longest first
  int by = (bid & 7) + ((bid >> 3) & 3) * 8;      // 0..31, by%8 == bid%8 (XCD pin)
  int b  = by >> 4, hh = by & 15;
  int lane = tid & 63, w = tid >> 6;
  int quad = lane >> 4, l15 = lane & 15;
  const __bf16* qb  = Qin  + (size_t)by * SEQ * DHEAD;
  const __bf16* kb  = Kin  + (size_t)by * SEQ * DHEAD;
  const __bf16* vtb = Vtin + (size_t)by * DHEAD * SEQ;
  const float L2E = 1.4426950408889634f;
  float slope = slopes[hh];
  const float c1 = 0.125f * L2E;
  float c2 = slope * L2E;
  float cjb[16];
#pragma unroll
  for(int jt=0;jt<4;jt++)
#pragma unroll
    for(int r=0;r<4;r++)
      cjb[jt*4+r] = c2 * (float)(jt*16 + quad*4 + r);

  int sxq0 = ((quad     ^ (l15 & 7)) << 3);   // d 0..31
  int sxq1 = (((quad+4) ^ (l15 & 7)) << 3);   // d 32..63

  int r8 = lane >> 3;              // 0..7 (row within group)
  int c8 = lane & 7;
  int sw = (c8 ^ r8) * 8;          // inverse-swizzled source chunk
  const __bf16* ksrc = kb  + (size_t)r8*DHEAD + sw;
  const __bf16* vsrc = vtb + (size_t)r8*SEQ  + sw;
  int g0 = w*2, g1 = w*2 + 1;
  const size_t kg0o = (size_t)g0*8*DHEAD, kg1o = (size_t)g1*8*DHEAD;
  const size_t vg0o = (size_t)g0*8*SEQ,   vg1o = (size_t)g1*8*SEQ;

  int q0 = qi * 64;
  int nst = qi + 1;                          // k-tiles of 64
  int i0 = q0 + w*16;
  int i  = i0 + l15;
  bf8 aq0 = *(const bf8*)(qb + (size_t)i*DHEAD + quad*8);
  bf8 aq1 = *(const bf8*)(qb + (size_t)i*DHEAD + 32 + quad*8);
  f4 oacc[4] = {};
  float l_ = 0.f;
  glds16(ksrc + kg0o, &Ks[0][g0*512]);
  glds16(ksrc + kg1o, &Ks[0][g1*512]);
  glds16(vsrc + vg0o, &Vts[0][g0*512]);
  glds16(vsrc + vg1o, &Vts[0][g1*512]);
  __syncthreads();
  int cur = 0;
  for(int t=0; t<nst; t++){
    int j0 = t*64;
    bool pf = (t+1) < nst;
    if(pf){
      int nb = cur ^ 1;
      size_t off = (size_t)(t+1)*64;
      glds16(ksrc + off*DHEAD + kg0o, &Ks[nb][g0*512]);
      glds16(ksrc + off*DHEAD + kg1o, &Ks[nb][g1*512]);
      glds16(vsrc + vg0o + off,       &Vts[nb][g0*512]);
      glds16(vsrc + vg1o + off,       &Vts[nb][g1*512]);
    }
    const __bf16* KsC  = Ks[cur];
    const __bf16* VtsC = Vts[cur];
    f4 s[4] = {};
    __builtin_amdgcn_s_setprio(1);
#pragma unroll
    for(int jt=0;jt<4;jt++){
      bf8 ak0 = *(const bf8*)&KsC[(jt*16+l15)*64 + sxq0];
      bf8 ak1 = *(const bf8*)&KsC[(jt*16+l15)*64 + sxq1];
      s[jt] = mfma16(ak0, aq0, s[jt]);
      s[jt] = mfma16(ak1, aq1, s[jt]);
    }
    __builtin_amdgcn_s_setprio(0);
    bf8 bv[2][4];
#pragma unroll
    for(int jk=0;jk<2;jk++)
#pragma unroll
      for(int nd=0;nd<4;nd++)
        bv[jk][nd] = *(const bf8*)&VtsC[(nd*16+l15)*64 + (((jk*4+quad) ^ (l15&7)) << 3)];
    float sv[4][4];
    if(t < nst-1){
      float cdi = c2 * (float)(i - j0) + 8.0f;
#pragma unroll
      for(int jt=0;jt<4;jt++)
#pragma unroll
        for(int r=0;r<4;r++)
          sv[jt][r] = fmaf(s[jt][r], c1, cjb[jt*4+r] - cdi);
    } else {
#pragma unroll
      for(int jt=0;jt<4;jt++)
#pragma unroll
        for(int r=0;r<4;r++){
          int j = j0 + jt*16 + quad*4 + r;
          int d = i - j;
          float val = fmaf(s[jt][r], c1, -fmaf(c2, (float)d, 8.0f));
          sv[jt][r] = (d < 0) ? -1e30f : val;
        }
    }
    float lsum = 0.f;
#pragma unroll
    for(int jt=0;jt<4;jt++){
      float p0 = __builtin_amdgcn_exp2f(sv[jt][0]);
      float p1 = __builtin_amdgcn_exp2f(sv[jt][1]);
      float p2 = __builtin_amdgcn_exp2f(sv[jt][2]);
      float p3 = __builtin_amdgcn_exp2f(sv[jt][3]);
      lsum += (p0+p1)+(p2+p3);
      uint2 pk = { pack2(p0,p1), pack2(p2,p3) };
      *(uint2*)&Ps[w][l15*72 + jt*16 + quad*4] = pk;
    }
    lsum += __shfl_xor(lsum, 16);
    lsum += __shfl_xor(lsum, 32);
    l_ += lsum;
    __builtin_amdgcn_s_setprio(1);
#pragma unroll
    for(int jk=0;jk<2;jk++){
      bf8 ap = *(const bf8*)&Ps[w][l15*72 + jk*32 + quad*8];
#pragma unroll
      for(int nd=0;nd<4;nd++)
        oacc[nd] = mfma16(ap, bv[jk][nd], oacc[nd]);
    }
    __builtin_amdgcn_s_setprio(0);
    __syncthreads();
    cur ^= 1;
  }
  if(quad == 0) Al[w][l15] = 1.0f / l_;
  f4 linv = *(const f4*)&Al[w][quad*4];
#pragma unroll
  for(int nd=0;nd<4;nd++)
#pragma unroll
    for(int r=0;r<4;r++){
      int io = i0 + quad*4 + r;
      Oout[((size_t)(b*SEQ + io))*DMODEL + hh*64 + nd*16 + l15] =
          (__bf16)(oacc[nd][r] * linv[r]);
    }
}

extern "C" void kernel_launch(void* const* d_in, const int* in_sizes, int n_in,
                              void* d_out, int out_size, void* d_ws, size_t ws_size,
                              hipStream_t stream){
  const float* x      = (const float*)d_in[0];
  const float* gam    = (const float*)d_in[1];
  const float* bet    = (const float*)d_in[2];
  const float* w_qkv  = (const float*)d_in[3];
  const float* slopes = (const float*)d_in[22];
  const float* w_out  = (const float*)d_in[23];
  float* out = (float*)d_out;

  // 48 MB workspace, aliased by liveness (proven at 48 MB):
  // [0,8)   h -> qpost
  // [8,32)  qkv -> att [8,16), wout_bf [24,26) (after conv)
  // [32,38) wqkv_bf -> kpost [32,40) (after gemm1)
  // [40,48) vtp (written by conv directly, transposed)
  char* ws = (char*)d_ws;
  __bf16* h       = (__bf16*)(ws);
  __bf16* qpost   = (__bf16*)(ws);
  __bf16* qkv     = (__bf16*)(ws + ((size_t)8  << 20));
  __bf16* att     = (__bf16*)(ws + ((size_t)8  << 20));
  __bf16* wout_bf = (__bf16*)(ws + ((size_t)24 << 20));
  __bf16* wqkv_bf = (__bf16*)(ws + ((size_t)32 << 20));
  __bf16* kpost   = (__bf16*)(ws + ((size_t)32 << 20));
  __bf16* vtp     = (__bf16*)(ws + ((size_t)40 << 20));

  constexpr int NQKV = 3 * DMODEL * DMODEL;

  prep_kernel<<<BATCH*SEQ + NQKV/4/256, 256, 0, stream>>>(x, gam, bet, h, w_qkv, wqkv_bf);
  gemm_nt<__bf16><<<dim3(E3/128, (BATCH*SEQ)/128), 256, 0, stream>>>(
      h, wqkv_bf, qkv, BATCH*SEQ, E3, DMODEL);
  conv_kernel<<<dim3(32, 12, BATCH), 256, 0, stream>>>(qkv, qpost, kpost, vtp,
    (const float*)d_in[4],(const float*)d_in[5],(const float*)d_in[6],(const float*)d_in[7],
    (const float*)d_in[8],(const float*)d_in[9],
    (const float*)d_in[10],(const float*)d_in[11],(const float*)d_in[12],(const float*)d_in[13],
    (const float*)d_in[14],(const float*)d_in[15],
    (const float*)d_in[16],(const float*)d_in[17],(const float*)d_in[18],(const float*)d_in[19],
    (const float*)d_in[20],(const float*)d_in[21]);
  attn_kernel<<<dim3(2048), 256, 0, stream>>>(qpost, kpost, vtp, slopes, att,
                                              w_out, wout_bf);
  gemm_nt<float><<<dim3(DMODEL/128, (BATCH*SEQ)/128), 256, 0, stream>>>(
      att, wout_bf, out, BATCH*SEQ, DMODEL, DMODEL);
}